// Round 4
// baseline (280.052 us; speedup 1.0000x reference)
//
#include <hip/hip_runtime.h>
#include <math.h>

// ---------------- problem constants (fixed by reference file) ----------------
#define N_TOK   2048      // NC * PY * PX
#define DIM     1024
#define HEADS   16
#define HD      64        // head dim
#define NCAMS   2
#define NPER    1024      // tokens per camera (32*32)
#define DPROJ   32        // first half: projective 4x4 groups
#define NF      8         // rope freqs
#define KSPLIT  4         // attention key-dim split

typedef _Float16 half8  __attribute__((ext_vector_type(8)));
typedef _Float16 half4h __attribute__((ext_vector_type(4)));
typedef _Float16 half2h __attribute__((ext_vector_type(2)));
typedef float    floatx4 __attribute__((ext_vector_type(4)));

// ---------------- workspace layout (float-granular offsets) ----------------
// mats | Wproj f16 | SCRATCH (Xf|Wqkv|qkv16 -> reused as OP|ML) | Q | K | Vt | Ot
#define MATS_OFF  0
#define WPROJ_OFF 256
#define SCR_OFF   (WPROJ_OFF + 524288)
#define XF_OFF    (SCR_OFF)                    // x f16: 2M halves = 1M fl
#define WQKV_OFF  (SCR_OFF + 1048576)          // qkv_w f16: 3M halves = 1.5M fl
#define QKV16_OFF (SCR_OFF + 2621440)          // qkv f16: 6M halves = 3M fl
#define OP_OFF    (SCR_OFF)                    // partial O f16: KSPLIT*2M halves = 4M fl
#define ML_OFF    (SCR_OFF + 4194304)          // m,l f32: KSPLIT*16*2048*2 = 256K fl
#define Q_OFF     (SCR_OFF + 5767168)          // f16 2M halves = 1M fl
#define K_OFF     (Q_OFF + 1048576)
#define V_OFF     (K_OFF + 1048576)
#define OT_OFF    (V_OFF + 1048576)            // f16 2M halves = 1M fl
// total ~= 10.5M floats ~= 40 MB

// ---------------- async global->LDS (16B per lane, wave-uniform LDS base) ----------------
__device__ __forceinline__ void gl_lds16(const void* g, void* s) {
    __builtin_amdgcn_global_load_lds((const __attribute__((address_space(1))) void*)g,
                                     (__attribute__((address_space(3))) void*)s, 16, 0, 0);
}

// ---------------- per-camera matrices ----------------
__global__ void build_mats(const float* __restrict__ ext, const float* __restrict__ Ks,
                           float* __restrict__ mats) {
    int c = threadIdx.x;
    if (c >= NCAMS) return;
    const float sx = 2.0f / 448.0f, sy = 2.0f / 448.0f;
    const float* Kc = Ks + c * 9;
    const float* E  = ext + c * 16;
    float Kn[16];
#pragma unroll
    for (int i = 0; i < 16; i++) Kn[i] = 0.0f;
    Kn[0]  = Kc[0] * sx;
    Kn[2]  = Kc[2] * sx - 1.0f;
    Kn[5]  = Kc[4] * sy;
    Kn[6]  = Kc[5] * sy - 1.0f;
    Kn[10] = 1.0f; Kn[15] = 1.0f;
    float P[16];
#pragma unroll
    for (int i = 0; i < 4; i++)
#pragma unroll
        for (int j = 0; j < 4; j++) {
            float s = 0.0f;
#pragma unroll
            for (int k = 0; k < 4; k++) s += Kn[i*4+k] * E[k*4+j];
            P[i*4+j] = s;
        }
    float M[4][8];
    for (int i = 0; i < 4; i++)
        for (int j = 0; j < 4; j++) { M[i][j] = P[i*4+j]; M[i][4+j] = (i==j) ? 1.0f : 0.0f; }
    for (int col = 0; col < 4; col++) {
        int piv = col;
        for (int r = col+1; r < 4; r++)
            if (fabsf(M[r][col]) > fabsf(M[piv][col])) piv = r;
        if (piv != col)
            for (int j = 0; j < 8; j++) { float tmp = M[col][j]; M[col][j] = M[piv][j]; M[piv][j] = tmp; }
        float d = 1.0f / M[col][col];
        for (int j = 0; j < 8; j++) M[col][j] *= d;
        for (int r = 0; r < 4; r++) {
            if (r == col) continue;
            float f = M[r][col];
            for (int j = 0; j < 8; j++) M[r][j] -= f * M[col][j];
        }
    }
    float Pi[16];
    for (int i = 0; i < 4; i++)
        for (int j = 0; j < 4; j++) Pi[i*4+j] = M[i][4+j];
    float* o = mats + c * 48;
    for (int i = 0; i < 4; i++)
        for (int j = 0; j < 4; j++) o[i*4+j] = Pi[j*4+i];   // Aq = Pinv^T
    for (int t = 0; t < 16; t++) o[16+t] = P[t];            // Ak = P
    for (int t = 0; t < 16; t++) o[32+t] = Pi[t];           // Ao = Pinv
}

// ---------------- cast x / qkv_w / proj_w to f16 ----------------
__global__ __launch_bounds__(256) void cast_inputs(const float* __restrict__ x,
                                                   const float* __restrict__ wqkv,
                                                   const float* __restrict__ wproj,
                                                   _Float16* __restrict__ xf,
                                                   _Float16* __restrict__ wqkvf,
                                                   _Float16* __restrict__ wprojf) {
    size_t i = ((size_t)blockIdx.x * 256 + threadIdx.x) * 8;
    const float* src; _Float16* dst; size_t off;
    if (i < (size_t)2*1024*1024)       { src = x;     dst = xf;     off = i; }
    else if (i < (size_t)5*1024*1024)  { src = wqkv;  dst = wqkvf;  off = i - (size_t)2*1024*1024; }
    else                               { src = wproj; dst = wprojf; off = i - (size_t)5*1024*1024; }
    float4 a = *(const float4*)(src + off);
    float4 b = *(const float4*)(src + off + 4);
    half8 h;
    h[0] = (_Float16)a.x; h[1] = (_Float16)a.y; h[2] = (_Float16)a.z; h[3] = (_Float16)a.w;
    h[4] = (_Float16)b.x; h[5] = (_Float16)b.y; h[6] = (_Float16)b.z; h[7] = (_Float16)b.w;
    *(half8*)(dst + off) = h;
}

// ---------------- MFMA f16 GEMM: C[M][Nn] = A[M][K] . B[Nn][K]^T ----------------
template <bool F16OUT>
__global__ __launch_bounds__(256) void gemm_mfma(const _Float16* __restrict__ A,
                                                 const _Float16* __restrict__ Bw,
                                                 const float* __restrict__ bias,
                                                 void* __restrict__ C,
                                                 int Nn, int Kd) {
    __shared__ _Float16 As[128 * 32];
    __shared__ _Float16 Bs[128 * 32];
    const int tid  = threadIdx.x;
    const int w    = tid >> 6, lane = tid & 63;
    const int ql   = lane & 15, quad = lane >> 4;
    const int lr   = lane >> 2, lc = lane & 3;
    const int wm   = w >> 1, wn = w & 1;
    const int row0 = blockIdx.y * 128, col0 = blockIdx.x * 128;

    floatx4 acc[4][4];
#pragma unroll
    for (int mt = 0; mt < 4; mt++)
#pragma unroll
        for (int nt = 0; nt < 4; nt++) acc[mt][nt] = (floatx4){0.f, 0.f, 0.f, 0.f};

    const _Float16* Ab = A  + (size_t)(row0 + w * 32 + lr) * Kd + lc * 8;
    const _Float16* Bb = Bw + (size_t)(col0 + w * 32 + lr) * Kd + lc * 8;
    _Float16* AsW = &As[(w * 32) * 32];
    _Float16* BsW = &Bs[(w * 32) * 32];

    for (int k0 = 0; k0 < Kd; k0 += 32) {
        gl_lds16(Ab + k0,            AsW);
        gl_lds16(Ab + 16 * Kd + k0,  AsW + 16 * 32);
        gl_lds16(Bb + k0,            BsW);
        gl_lds16(Bb + 16 * Kd + k0,  BsW + 16 * 32);
        __syncthreads();
        half8 af[4], bf[4];
#pragma unroll
        for (int mt = 0; mt < 4; mt++)
            af[mt] = *(const half8*)&As[(wm * 64 + mt * 16 + ql) * 32 + quad * 8];
#pragma unroll
        for (int nt = 0; nt < 4; nt++)
            bf[nt] = *(const half8*)&Bs[(wn * 64 + nt * 16 + ql) * 32 + quad * 8];
#pragma unroll
        for (int mt = 0; mt < 4; mt++)
#pragma unroll
            for (int nt = 0; nt < 4; nt++)
                acc[mt][nt] = __builtin_amdgcn_mfma_f32_16x16x32_f16(af[mt], bf[nt], acc[mt][nt], 0, 0, 0);
        __syncthreads();
    }

#pragma unroll
    for (int nt = 0; nt < 4; nt++) {
        const int col = col0 + wn * 64 + nt * 16 + ql;
        float bb = F16OUT ? 0.0f : bias[col];
#pragma unroll
        for (int mt = 0; mt < 4; mt++) {
            const int row = row0 + wm * 64 + mt * 16 + quad * 4;
            if (F16OUT) {
                _Float16* Cp = (_Float16*)C;
#pragma unroll
                for (int r = 0; r < 4; r++)
                    Cp[(size_t)(row + r) * Nn + col] = (_Float16)acc[mt][nt][r];
            } else {
                float* Cp = (float*)C;
#pragma unroll
                for (int r = 0; r < 4; r++)
                    Cp[(size_t)(row + r) * Nn + col] = acc[mt][nt][r] + bb;
            }
        }
    }
}

// ---------------- PRoPE transform: thread per 8 dims, no cross-lane ops ----------------
// T = ((n*3 + s)*16 + h)*8 + sub
__global__ __launch_bounds__(256) void transform_qkv(const _Float16* __restrict__ qkv,
                                                     const float* __restrict__ mats,
                                                     _Float16* __restrict__ Qf,
                                                     _Float16* __restrict__ Kf,
                                                     _Float16* __restrict__ Vtf) {
    const int T = blockIdx.x * 256 + threadIdx.x;
    const int sub = T & 7;
    const int h   = (T >> 3) & 15;
    const int s   = (T >> 7) % 3;
    const int n   = T / 384;

    half8 v = *(const half8*)&qkv[(size_t)n * (3*DIM) + s * DIM + h * HD + sub * 8];
    float t[8];
#pragma unroll
    for (int i = 0; i < 8; i++) t[i] = (float)v[i];

    const int cam = n >> 10;
    const float* A = mats + cam * 48 + (s == 0 ? 0 : 16);
    float r[8];
    if (sub < 4) {
#pragma unroll
        for (int g = 0; g < 2; g++)
#pragma unroll
            for (int i = 0; i < 4; i++)
                r[g*4+i] = A[i*4+0]*t[g*4+0] + A[i*4+1]*t[g*4+1]
                         + A[i*4+2]*t[g*4+2] + A[i*4+3]*t[g*4+3];
    } else {
        const int p = n & (NPER - 1);
        const float px = (float)(p & 31), py = (float)(p >> 5);
        const int pt0 = (sub - 4) * 4;
#pragma unroll
        for (int pp = 0; pp < 4; pp++) {
            const int pt = pt0 + pp;
            const float fr = __expf(-0.5756462732485114f * (float)(pt & 7)); // 100^(-j/8)
            const float ang = (pt < NF ? px : py) * fr;
            float sn, cs; __sincosf(ang, &sn, &cs);
            const float a = t[pp*2], b = t[pp*2+1];
            r[pp*2]   = a * cs - b * sn;
            r[pp*2+1] = a * sn + b * cs;
        }
    }

    if (s == 0) {
        half8 o;
#pragma unroll
        for (int i = 0; i < 8; i++) o[i] = (_Float16)(r[i] * 0.125f);  // fold 1/sqrt(64)
        *(half8*)&Qf[((size_t)h * N_TOK + n) * HD + sub * 8] = o;
    } else if (s == 1) {
        half8 o;
#pragma unroll
        for (int i = 0; i < 8; i++) o[i] = (_Float16)r[i];
        *(half8*)&Kf[((size_t)h * N_TOK + n) * HD + sub * 8] = o;
    } else {
#pragma unroll
        for (int i = 0; i < 8; i++)
            Vtf[((size_t)h * HD + sub * 8 + i) * N_TOK + n] = (_Float16)r[i]; // [h][d][n]
    }
}

// ---------------- MFMA flash attention, split-K ----------------
// block b: ks = b>>9, hh = (b>>5)&15, qb = b&31. 4 waves x 16 q-rows. 512 keys/block.
// Writes normalized partial O (f16) + (m,l) f32 per (ks, head, q).
#define PLD 68
__global__ __launch_bounds__(256) void attn_mfma(const _Float16* __restrict__ Qh,
                                                 const _Float16* __restrict__ Kh,
                                                 const _Float16* __restrict__ Vt,
                                                 _Float16* __restrict__ OP,
                                                 float* __restrict__ ML) {
    __shared__ _Float16 P_lds[4][16][PLD];
    const int w    = threadIdx.x >> 6;
    const int lane = threadIdx.x & 63;
    const int b  = blockIdx.x;
    const int ks = b >> 9;
    const int hh = (b >> 5) & 15;
    const int qb = b & 31;
    const int ql = lane & 15, quad = lane >> 4;
    const int q0 = qb * 64 + w * 16;

    const _Float16* Qp = Qh + ((size_t)hh * N_TOK + q0 + ql) * HD;
    const half8 qf0 = *(const half8*)(Qp + quad * 8);
    const half8 qf1 = *(const half8*)(Qp + 32 + quad * 8);

    const _Float16* Kb = Kh + (size_t)hh * N_TOK * HD;
    const _Float16* Vb = Vt + (size_t)hh * HD * N_TOK;

    floatx4 O[4];
#pragma unroll
    for (int mt = 0; mt < 4; mt++) O[mt] = (floatx4){0.f, 0.f, 0.f, 0.f};
    float m = -1e30f, l = 0.0f;

    const int kend = ks * (N_TOK / KSPLIT) + (N_TOK / KSPLIT);
    for (int kb = ks * (N_TOK / KSPLIT); kb < kend; kb += 64) {
        floatx4 s[4];
#pragma unroll
        for (int kt = 0; kt < 4; kt++) {
            const _Float16* Kp = Kb + (size_t)(kb + kt * 16 + ql) * HD;
            half8 ka0 = *(const half8*)(Kp + quad * 8);
            half8 ka1 = *(const half8*)(Kp + 32 + quad * 8);
            floatx4 acc = (floatx4){0.f, 0.f, 0.f, 0.f};
            acc = __builtin_amdgcn_mfma_f32_16x16x32_f16(ka0, qf0, acc, 0, 0, 0);
            acc = __builtin_amdgcn_mfma_f32_16x16x32_f16(ka1, qf1, acc, 0, 0, 0);
            s[kt] = acc;
        }
        float bm = -1e30f;
#pragma unroll
        for (int kt = 0; kt < 4; kt++)
#pragma unroll
            for (int r = 0; r < 4; r++) bm = fmaxf(bm, s[kt][r]);
        bm = fmaxf(bm, __shfl_xor(bm, 16, 64));
        bm = fmaxf(bm, __shfl_xor(bm, 32, 64));
        const float mnew = fmaxf(m, bm);
        const float alpha = __expf(m - mnew);
        float p[4][4];
        float ps = 0.0f;
#pragma unroll
        for (int kt = 0; kt < 4; kt++)
#pragma unroll
            for (int r = 0; r < 4; r++) { p[kt][r] = __expf(s[kt][r] - mnew); ps += p[kt][r]; }
        ps += __shfl_xor(ps, 16, 64);
        ps += __shfl_xor(ps, 32, 64);
        l = l * alpha + ps;
        m = mnew;
#pragma unroll
        for (int mt = 0; mt < 4; mt++)
#pragma unroll
            for (int r = 0; r < 4; r++) O[mt][r] *= alpha;
#pragma unroll
        for (int kt = 0; kt < 4; kt++) {
            half2h p01 = {(_Float16)p[kt][0], (_Float16)p[kt][1]};
            half2h p23 = {(_Float16)p[kt][2], (_Float16)p[kt][3]};
            *(half2h*)&P_lds[w][ql][kt * 16 + quad * 4]     = p01;
            *(half2h*)&P_lds[w][ql][kt * 16 + quad * 4 + 2] = p23;
        }
        half4h pa = *(const half4h*)&P_lds[w][ql][quad * 8];
        half4h pb = *(const half4h*)&P_lds[w][ql][quad * 8 + 4];
        half4h pc = *(const half4h*)&P_lds[w][ql][32 + quad * 8];
        half4h pd = *(const half4h*)&P_lds[w][ql][32 + quad * 8 + 4];
        half8 pf0, pf1;
#pragma unroll
        for (int j = 0; j < 4; j++) { pf0[j] = pa[j]; pf0[4 + j] = pb[j]; pf1[j] = pc[j]; pf1[4 + j] = pd[j]; }
#pragma unroll
        for (int mt = 0; mt < 4; mt++) {
            const _Float16* Vp = Vb + (size_t)(mt * 16 + ql) * N_TOK + kb;
            half8 va0 = *(const half8*)(Vp + quad * 8);
            half8 va1 = *(const half8*)(Vp + 32 + quad * 8);
            O[mt] = __builtin_amdgcn_mfma_f32_16x16x32_f16(va0, pf0, O[mt], 0, 0, 0);
            O[mt] = __builtin_amdgcn_mfma_f32_16x16x32_f16(va1, pf1, O[mt], 0, 0, 0);
        }
    }
    const float rl = 1.0f / l;
    _Float16* Op = OP + (((size_t)(ks * HEADS + hh)) * N_TOK + q0 + ql) * HD;
#pragma unroll
    for (int mt = 0; mt < 4; mt++) {
        half4h o4;
#pragma unroll
        for (int r = 0; r < 4; r++) o4[r] = (_Float16)(O[mt][r] * rl);
        *(half4h*)&Op[mt * 16 + quad * 4] = o4;
    }
    if (quad == 0) {
        float2 mlv = {m, l};
        *(float2*)&ML[(((size_t)(ks * HEADS + hh)) * N_TOK + q0 + ql) * 2] = mlv;
    }
}

// ---------------- combine split-K partials + inverse PRoPE -> f16 token-major ----------------
// T = (n*16 + h)*8 + sub
__global__ __launch_bounds__(256) void transform_out(const _Float16* __restrict__ OP,
                                                     const float* __restrict__ ML,
                                                     const float* __restrict__ mats,
                                                     _Float16* __restrict__ Ot) {
    const int T = blockIdx.x * 256 + threadIdx.x;
    const int sub = T & 7;
    const int h   = (T >> 3) & 15;
    const int n   = T >> 7;

    half8 op[KSPLIT];
    float2 ml[KSPLIT];
#pragma unroll
    for (int i = 0; i < KSPLIT; i++) {
        op[i] = *(const half8*)&OP[(((size_t)(i * HEADS + h)) * N_TOK + n) * HD + sub * 8];
        ml[i] = *(const float2*)&ML[(((size_t)(i * HEADS + h)) * N_TOK + n) * 2];
    }
    float mstar = ml[0].x;
#pragma unroll
    for (int i = 1; i < KSPLIT; i++) mstar = fmaxf(mstar, ml[i].x);
    float W = 0.0f;
    float t[8] = {0.f, 0.f, 0.f, 0.f, 0.f, 0.f, 0.f, 0.f};
#pragma unroll
    for (int i = 0; i < KSPLIT; i++) {
        const float wgt = __expf(ml[i].x - mstar) * ml[i].y;
        W += wgt;
#pragma unroll
        for (int d = 0; d < 8; d++) t[d] += wgt * (float)op[i][d];
    }
    const float rW = 1.0f / W;
#pragma unroll
    for (int d = 0; d < 8; d++) t[d] *= rW;

    const int cam = n >> 10;
    const float* A = mats + cam * 48 + 32;   // Ao = Pinv
    float r[8];
    if (sub < 4) {
#pragma unroll
        for (int g = 0; g < 2; g++)
#pragma unroll
            for (int i = 0; i < 4; i++)
                r[g*4+i] = A[i*4+0]*t[g*4+0] + A[i*4+1]*t[g*4+1]
                         + A[i*4+2]*t[g*4+2] + A[i*4+3]*t[g*4+3];
    } else {
        const int p = n & (NPER - 1);
        const float px = (float)(p & 31), py = (float)(p >> 5);
        const int pt0 = (sub - 4) * 4;
#pragma unroll
        for (int pp = 0; pp < 4; pp++) {
            const int pt = pt0 + pp;
            const float fr = __expf(-0.5756462732485114f * (float)(pt & 7));
            const float ang = (pt < NF ? px : py) * fr;
            float sn, cs; __sincosf(ang, &sn, &cs);
            const float a = t[pp*2], b = t[pp*2+1];
            r[pp*2]   = a * cs + b * sn;    // sign = -1
            r[pp*2+1] = -a * sn + b * cs;
        }
    }
    half8 o;
#pragma unroll
    for (int i = 0; i < 8; i++) o[i] = (_Float16)r[i];
    *(half8*)&Ot[(size_t)n * DIM + h * HD + sub * 8] = o;
}

// ---------------- launcher ----------------
extern "C" void kernel_launch(void* const* d_in, const int* in_sizes, int n_in,
                              void* d_out, int out_size, void* d_ws, size_t ws_size,
                              hipStream_t stream) {
    const float* x      = (const float*)d_in[0];
    const float* ext    = (const float*)d_in[1];
    const float* Ks     = (const float*)d_in[2];
    const float* qkv_w  = (const float*)d_in[3];
    const float* proj_w = (const float*)d_in[4];
    const float* proj_b = (const float*)d_in[5];
    float* out = (float*)d_out;

    float* ws   = (float*)d_ws;
    float* mats = ws + MATS_OFF;
    _Float16* Wprojf = (_Float16*)(ws + WPROJ_OFF);
    _Float16* Xf     = (_Float16*)(ws + XF_OFF);
    _Float16* Wqkvf  = (_Float16*)(ws + WQKV_OFF);
    _Float16* qkv16  = (_Float16*)(ws + QKV16_OFF);
    _Float16* OP     = (_Float16*)(ws + OP_OFF);
    float*    ML     = ws + ML_OFF;
    _Float16* Qf  = (_Float16*)(ws + Q_OFF);
    _Float16* Kf  = (_Float16*)(ws + K_OFF);
    _Float16* Vtf = (_Float16*)(ws + V_OFF);
    _Float16* Ot16 = (_Float16*)(ws + OT_OFF);

    build_mats<<<1, 64, 0, stream>>>(ext, Ks, mats);

    cast_inputs<<<3072, 256, 0, stream>>>(x, qkv_w, proj_w, Xf, Wqkvf, Wprojf);

    // qkv16 = x @ qkv_w^T : M=2048, Nn=3072, K=1024
    gemm_mfma<true><<<dim3(3*DIM/128, N_TOK/128), 256, 0, stream>>>(
        Xf, Wqkvf, nullptr, (void*)qkv16, 3*DIM, DIM);

    transform_qkv<<<N_TOK * 3 * HEADS * 8 / 256, 256, 0, stream>>>(qkv16, mats, Qf, Kf, Vtf);

    attn_mfma<<<KSPLIT * HEADS * (N_TOK / 64), 256, 0, stream>>>(Qf, Kf, Vtf, OP, ML);

    transform_out<<<N_TOK * HEADS * 8 / 256, 256, 0, stream>>>(OP, ML, mats, Ot16);

    // out = Ot @ proj_w^T + proj_b : M=2048, Nn=1024, K=1024
    gemm_mfma<false><<<dim3(DIM/128, N_TOK/128), 256, 0, stream>>>(
        Ot16, Wprojf, proj_b, (void*)out, DIM, DIM);
}

// Round 5
// 279.913 us; speedup vs baseline: 1.0005x; 1.0005x over previous
//
#include <hip/hip_runtime.h>
#include <math.h>

// ---------------- problem constants (fixed by reference file) ----------------
#define N_TOK   2048      // NC * PY * PX
#define DIM     1024
#define HEADS   16
#define HD      64        // head dim
#define NCAMS   2
#define NPER    1024      // tokens per camera (32*32)
#define DPROJ   32        // first half: projective 4x4 groups
#define NF      8         // rope freqs
#define KSPLIT  2         // attention key-dim split

typedef _Float16 half8  __attribute__((ext_vector_type(8)));
typedef _Float16 half4h __attribute__((ext_vector_type(4)));
typedef _Float16 half2h __attribute__((ext_vector_type(2)));
typedef float    floatx4 __attribute__((ext_vector_type(4)));

// ---------------- workspace layout (float-granular offsets) ----------------
#define MATS_OFF  0
#define WPROJ_OFF 256
#define SCR_OFF   (WPROJ_OFF + 524288)
#define XF_OFF    (SCR_OFF)                    // x f16: 2M halves = 1M fl
#define WQKV_OFF  (SCR_OFF + 1048576)          // qkv_w f16: 3M halves = 1.5M fl
#define QKV16_OFF (SCR_OFF + 2621440)          // qkv f16: 6M halves = 3M fl
#define OP_OFF    (SCR_OFF)                    // partial O f16: <=4*2M halves
#define ML_OFF    (SCR_OFF + 4194304)          // m,l f32
#define Q_OFF     (SCR_OFF + 5767168)          // f16 2M halves = 1M fl
#define K_OFF     (Q_OFF + 1048576)
#define V_OFF     (K_OFF + 1048576)
#define OT_OFF    (V_OFF + 1048576)            // f16 2M halves
// total ~= 10.5M floats ~= 40 MB

// ---------------- async global->LDS (16B per lane, wave-uniform LDS base) ----------------
__device__ __forceinline__ void gl_lds16(const void* g, void* s) {
    __builtin_amdgcn_global_load_lds((const __attribute__((address_space(1))) void*)g,
                                     (__attribute__((address_space(3))) void*)s, 16, 0, 0);
}

// ---------------- per-camera matrices ----------------
__global__ void build_mats(const float* __restrict__ ext, const float* __restrict__ Ks,
                           float* __restrict__ mats) {
    int c = threadIdx.x;
    if (c >= NCAMS) return;
    const float sx = 2.0f / 448.0f, sy = 2.0f / 448.0f;
    const float* Kc = Ks + c * 9;
    const float* E  = ext + c * 16;
    float Kn[16];
#pragma unroll
    for (int i = 0; i < 16; i++) Kn[i] = 0.0f;
    Kn[0]  = Kc[0] * sx;
    Kn[2]  = Kc[2] * sx - 1.0f;
    Kn[5]  = Kc[4] * sy;
    Kn[6]  = Kc[5] * sy - 1.0f;
    Kn[10] = 1.0f; Kn[15] = 1.0f;
    float P[16];
#pragma unroll
    for (int i = 0; i < 4; i++)
#pragma unroll
        for (int j = 0; j < 4; j++) {
            float s = 0.0f;
#pragma unroll
            for (int k = 0; k < 4; k++) s += Kn[i*4+k] * E[k*4+j];
            P[i*4+j] = s;
        }
    float M[4][8];
    for (int i = 0; i < 4; i++)
        for (int j = 0; j < 4; j++) { M[i][j] = P[i*4+j]; M[i][4+j] = (i==j) ? 1.0f : 0.0f; }
    for (int col = 0; col < 4; col++) {
        int piv = col;
        for (int r = col+1; r < 4; r++)
            if (fabsf(M[r][col]) > fabsf(M[piv][col])) piv = r;
        if (piv != col)
            for (int j = 0; j < 8; j++) { float tmp = M[col][j]; M[col][j] = M[piv][j]; M[piv][j] = tmp; }
        float d = 1.0f / M[col][col];
        for (int j = 0; j < 8; j++) M[col][j] *= d;
        for (int r = 0; r < 4; r++) {
            if (r == col) continue;
            float f = M[r][col];
            for (int j = 0; j < 8; j++) M[r][j] -= f * M[col][j];
        }
    }
    float Pi[16];
    for (int i = 0; i < 4; i++)
        for (int j = 0; j < 4; j++) Pi[i*4+j] = M[i][4+j];
    float* o = mats + c * 48;
    for (int i = 0; i < 4; i++)
        for (int j = 0; j < 4; j++) o[i*4+j] = Pi[j*4+i];   // Aq = Pinv^T
    for (int t = 0; t < 16; t++) o[16+t] = P[t];            // Ak = P
    for (int t = 0; t < 16; t++) o[32+t] = Pi[t];           // Ao = Pinv
}

// ---------------- cast x / qkv_w / proj_w to f16 ----------------
__global__ __launch_bounds__(256) void cast_inputs(const float* __restrict__ x,
                                                   const float* __restrict__ wqkv,
                                                   const float* __restrict__ wproj,
                                                   _Float16* __restrict__ xf,
                                                   _Float16* __restrict__ wqkvf,
                                                   _Float16* __restrict__ wprojf) {
    size_t i = ((size_t)blockIdx.x * 256 + threadIdx.x) * 8;
    const float* src; _Float16* dst; size_t off;
    if (i < (size_t)2*1024*1024)       { src = x;     dst = xf;     off = i; }
    else if (i < (size_t)5*1024*1024)  { src = wqkv;  dst = wqkvf;  off = i - (size_t)2*1024*1024; }
    else                               { src = wproj; dst = wprojf; off = i - (size_t)5*1024*1024; }
    float4 a = *(const float4*)(src + off);
    float4 b = *(const float4*)(src + off + 4);
    half8 h;
    h[0] = (_Float16)a.x; h[1] = (_Float16)a.y; h[2] = (_Float16)a.z; h[3] = (_Float16)a.w;
    h[4] = (_Float16)b.x; h[5] = (_Float16)b.y; h[6] = (_Float16)b.z; h[7] = (_Float16)b.w;
    *(half8*)(dst + off) = h;
}

// ---------------- MFMA f16 GEMM: C[M][Nn] = A[M][K] . B[Nn][K]^T ----------------
template <bool F16OUT>
__global__ __launch_bounds__(256) void gemm_mfma(const _Float16* __restrict__ A,
                                                 const _Float16* __restrict__ Bw,
                                                 const float* __restrict__ bias,
                                                 void* __restrict__ C,
                                                 int Nn, int Kd) {
    __shared__ _Float16 As[128 * 32];
    __shared__ _Float16 Bs[128 * 32];
    const int tid  = threadIdx.x;
    const int w    = tid >> 6, lane = tid & 63;
    const int ql   = lane & 15, quad = lane >> 4;
    const int lr   = lane >> 2, lc = lane & 3;
    const int wm   = w >> 1, wn = w & 1;
    const int row0 = blockIdx.y * 128, col0 = blockIdx.x * 128;

    floatx4 acc[4][4];
#pragma unroll
    for (int mt = 0; mt < 4; mt++)
#pragma unroll
        for (int nt = 0; nt < 4; nt++) acc[mt][nt] = (floatx4){0.f, 0.f, 0.f, 0.f};

    const _Float16* Ab = A  + (size_t)(row0 + w * 32 + lr) * Kd + lc * 8;
    const _Float16* Bb = Bw + (size_t)(col0 + w * 32 + lr) * Kd + lc * 8;
    _Float16* AsW = &As[(w * 32) * 32];
    _Float16* BsW = &Bs[(w * 32) * 32];

    for (int k0 = 0; k0 < Kd; k0 += 32) {
        gl_lds16(Ab + k0,            AsW);
        gl_lds16(Ab + 16 * Kd + k0,  AsW + 16 * 32);
        gl_lds16(Bb + k0,            BsW);
        gl_lds16(Bb + 16 * Kd + k0,  BsW + 16 * 32);
        __syncthreads();
        half8 af[4], bf[4];
#pragma unroll
        for (int mt = 0; mt < 4; mt++)
            af[mt] = *(const half8*)&As[(wm * 64 + mt * 16 + ql) * 32 + quad * 8];
#pragma unroll
        for (int nt = 0; nt < 4; nt++)
            bf[nt] = *(const half8*)&Bs[(wn * 64 + nt * 16 + ql) * 32 + quad * 8];
#pragma unroll
        for (int mt = 0; mt < 4; mt++)
#pragma unroll
            for (int nt = 0; nt < 4; nt++)
                acc[mt][nt] = __builtin_amdgcn_mfma_f32_16x16x32_f16(af[mt], bf[nt], acc[mt][nt], 0, 0, 0);
        __syncthreads();
    }

#pragma unroll
    for (int nt = 0; nt < 4; nt++) {
        const int col = col0 + wn * 64 + nt * 16 + ql;
        float bb = F16OUT ? 0.0f : bias[col];
#pragma unroll
        for (int mt = 0; mt < 4; mt++) {
            const int row = row0 + wm * 64 + mt * 16 + quad * 4;
            if (F16OUT) {
                _Float16* Cp = (_Float16*)C;
#pragma unroll
                for (int r = 0; r < 4; r++)
                    Cp[(size_t)(row + r) * Nn + col] = (_Float16)acc[mt][nt][r];
            } else {
                float* Cp = (float*)C;
#pragma unroll
                for (int r = 0; r < 4; r++)
                    Cp[(size_t)(row + r) * Nn + col] = acc[mt][nt][r] + bb;
            }
        }
    }
}

// ---------------- PRoPE transform: thread per 8 dims, no cross-lane ops ----------------
__global__ __launch_bounds__(256) void transform_qkv(const _Float16* __restrict__ qkv,
                                                     const float* __restrict__ mats,
                                                     _Float16* __restrict__ Qf,
                                                     _Float16* __restrict__ Kf,
                                                     _Float16* __restrict__ Vtf) {
    const int T = blockIdx.x * 256 + threadIdx.x;
    const int sub = T & 7;
    const int h   = (T >> 3) & 15;
    const int s   = (T >> 7) % 3;
    const int n   = T / 384;

    half8 v = *(const half8*)&qkv[(size_t)n * (3*DIM) + s * DIM + h * HD + sub * 8];
    float t[8];
#pragma unroll
    for (int i = 0; i < 8; i++) t[i] = (float)v[i];

    const int cam = n >> 10;
    const float* A = mats + cam * 48 + (s == 0 ? 0 : 16);
    float r[8];
    if (sub < 4) {
#pragma unroll
        for (int g = 0; g < 2; g++)
#pragma unroll
            for (int i = 0; i < 4; i++)
                r[g*4+i] = A[i*4+0]*t[g*4+0] + A[i*4+1]*t[g*4+1]
                         + A[i*4+2]*t[g*4+2] + A[i*4+3]*t[g*4+3];
    } else {
        const int p = n & (NPER - 1);
        const float px = (float)(p & 31), py = (float)(p >> 5);
        const int pt0 = (sub - 4) * 4;
#pragma unroll
        for (int pp = 0; pp < 4; pp++) {
            const int pt = pt0 + pp;
            const float fr = __expf(-0.5756462732485114f * (float)(pt & 7)); // 100^(-j/8)
            const float ang = (pt < NF ? px : py) * fr;
            float sn, cs; __sincosf(ang, &sn, &cs);
            const float a = t[pp*2], b = t[pp*2+1];
            r[pp*2]   = a * cs - b * sn;
            r[pp*2+1] = a * sn + b * cs;
        }
    }

    if (s == 0) {
        half8 o;
#pragma unroll
        for (int i = 0; i < 8; i++) o[i] = (_Float16)(r[i] * 0.125f);  // fold 1/sqrt(64)
        *(half8*)&Qf[((size_t)h * N_TOK + n) * HD + sub * 8] = o;
    } else if (s == 1) {
        half8 o;
#pragma unroll
        for (int i = 0; i < 8; i++) o[i] = (_Float16)r[i];
        *(half8*)&Kf[((size_t)h * N_TOK + n) * HD + sub * 8] = o;
    } else {
#pragma unroll
        for (int i = 0; i < 8; i++)
            Vtf[((size_t)h * HD + sub * 8 + i) * N_TOK + n] = (_Float16)r[i]; // [h][d][n]
    }
}

// ---------------- MFMA flash attention, split-K, software-pipelined ----------------
// block b: ks = top bits, hh, qb. 4 waves x 16 q-rows. N_TOK/KSPLIT keys per block.
// Depth-2 pipeline: K-tile i+1 loads issued at top of iter i; V-tile i loads issued
// before the softmax chain so their latency is covered by it.
#define PLD 68
__global__ __launch_bounds__(256) void attn_mfma(const _Float16* __restrict__ Qh,
                                                 const _Float16* __restrict__ Kh,
                                                 const _Float16* __restrict__ Vt,
                                                 _Float16* __restrict__ OP,
                                                 float* __restrict__ ML) {
    __shared__ _Float16 P_lds[4][16][PLD];
    const int w    = threadIdx.x >> 6;
    const int lane = threadIdx.x & 63;
    const int b  = blockIdx.x;
    const int ks = b >> 9;
    const int hh = (b >> 5) & 15;
    const int qb = b & 31;
    const int ql = lane & 15, quad = lane >> 4;
    const int q0 = qb * 64 + w * 16;

    const _Float16* Qp = Qh + ((size_t)hh * N_TOK + q0 + ql) * HD;
    const half8 qf0 = *(const half8*)(Qp + quad * 8);
    const half8 qf1 = *(const half8*)(Qp + 32 + quad * 8);

    const _Float16* Kb = Kh + (size_t)hh * N_TOK * HD;
    const _Float16* Vb = Vt + (size_t)hh * HD * N_TOK;

    floatx4 O[4];
#pragma unroll
    for (int mt = 0; mt < 4; mt++) O[mt] = (floatx4){0.f, 0.f, 0.f, 0.f};
    float m = -1e30f, l = 0.0f;   // l is LANE-LOCAL; reduced across quads after the loop

    const int kstart = ks * (N_TOK / KSPLIT);
    const int kend   = kstart + (N_TOK / KSPLIT);

    // ---- prologue: K-tile 0 in flight ----
    half8 kc[8];   // current K tile fragments (4 kt x 2 halves-of-dim)
#pragma unroll
    for (int kt = 0; kt < 4; kt++) {
        const _Float16* Kp = Kb + (size_t)(kstart + kt * 16 + ql) * HD;
        kc[kt * 2]     = *(const half8*)(Kp + quad * 8);
        kc[kt * 2 + 1] = *(const half8*)(Kp + 32 + quad * 8);
    }

    for (int kb = kstart; kb < kend; kb += 64) {
        // ---- prefetch next K tile (wrap on last iter; loads valid mem, unused) ----
        const int kbn = (kb + 64 < kend) ? kb + 64 : kstart;
        half8 kn[8];
#pragma unroll
        for (int kt = 0; kt < 4; kt++) {
            const _Float16* Kp = Kb + (size_t)(kbn + kt * 16 + ql) * HD;
            kn[kt * 2]     = *(const half8*)(Kp + quad * 8);
            kn[kt * 2 + 1] = *(const half8*)(Kp + 32 + quad * 8);
        }
        // ---- prefetch V tile for THIS iteration (consumed after softmax) ----
        half8 va[8];
#pragma unroll
        for (int mt = 0; mt < 4; mt++) {
            const _Float16* Vp = Vb + (size_t)(mt * 16 + ql) * N_TOK + kb;
            va[mt * 2]     = *(const half8*)(Vp + quad * 8);
            va[mt * 2 + 1] = *(const half8*)(Vp + 32 + quad * 8);
        }
        // ---- S^T = K . Q^T (uses current tile regs, loaded an iteration ago) ----
        floatx4 s[4];
#pragma unroll
        for (int kt = 0; kt < 4; kt++) {
            floatx4 acc = (floatx4){0.f, 0.f, 0.f, 0.f};
            acc = __builtin_amdgcn_mfma_f32_16x16x32_f16(kc[kt * 2],     qf0, acc, 0, 0, 0);
            acc = __builtin_amdgcn_mfma_f32_16x16x32_f16(kc[kt * 2 + 1], qf1, acc, 0, 0, 0);
            s[kt] = acc;
        }
        // ---- online softmax: only the 2 m-shuffles are cross-lane ----
        float bm = -1e30f;
#pragma unroll
        for (int kt = 0; kt < 4; kt++)
#pragma unroll
            for (int r = 0; r < 4; r++) bm = fmaxf(bm, s[kt][r]);
        bm = fmaxf(bm, __shfl_xor(bm, 16, 64));
        bm = fmaxf(bm, __shfl_xor(bm, 32, 64));
        const float mnew = fmaxf(m, bm);
        const float alpha = __expf(m - mnew);
        float p[4][4];
        float ps = 0.0f;
#pragma unroll
        for (int kt = 0; kt < 4; kt++)
#pragma unroll
            for (int r = 0; r < 4; r++) { p[kt][r] = __expf(s[kt][r] - mnew); ps += p[kt][r]; }
        l = l * alpha + ps;          // lane-local
        m = mnew;
#pragma unroll
        for (int mt = 0; mt < 4; mt++)
#pragma unroll
            for (int r = 0; r < 4; r++) O[mt][r] *= alpha;
        // ---- P -> per-wave LDS strip -> B-fragments ----
#pragma unroll
        for (int kt = 0; kt < 4; kt++) {
            half2h p01 = {(_Float16)p[kt][0], (_Float16)p[kt][1]};
            half2h p23 = {(_Float16)p[kt][2], (_Float16)p[kt][3]};
            *(half2h*)&P_lds[w][ql][kt * 16 + quad * 4]     = p01;
            *(half2h*)&P_lds[w][ql][kt * 16 + quad * 4 + 2] = p23;
        }
        half4h pa = *(const half4h*)&P_lds[w][ql][quad * 8];
        half4h pb = *(const half4h*)&P_lds[w][ql][quad * 8 + 4];
        half4h pc = *(const half4h*)&P_lds[w][ql][32 + quad * 8];
        half4h pd = *(const half4h*)&P_lds[w][ql][32 + quad * 8 + 4];
        half8 pf0, pf1;
#pragma unroll
        for (int j = 0; j < 4; j++) { pf0[j] = pa[j]; pf0[4 + j] = pb[j]; pf1[j] = pc[j]; pf1[4 + j] = pd[j]; }
        // ---- O^T += V^T . P  (va issued ~600 cyc earlier) ----
#pragma unroll
        for (int mt = 0; mt < 4; mt++) {
            O[mt] = __builtin_amdgcn_mfma_f32_16x16x32_f16(va[mt * 2],     pf0, O[mt], 0, 0, 0);
            O[mt] = __builtin_amdgcn_mfma_f32_16x16x32_f16(va[mt * 2 + 1], pf1, O[mt], 0, 0, 0);
        }
        // ---- rotate pipeline regs ----
#pragma unroll
        for (int i = 0; i < 8; i++) kc[i] = kn[i];
    }
    // ---- final cross-quad l reduction ----
    l += __shfl_xor(l, 16, 64);
    l += __shfl_xor(l, 32, 64);
    const float rl = 1.0f / l;
    _Float16* Op = OP + (((size_t)(ks * HEADS + hh)) * N_TOK + q0 + ql) * HD;
#pragma unroll
    for (int mt = 0; mt < 4; mt++) {
        half4h o4;
#pragma unroll
        for (int r = 0; r < 4; r++) o4[r] = (_Float16)(O[mt][r] * rl);
        *(half4h*)&Op[mt * 16 + quad * 4] = o4;
    }
    if (quad == 0) {
        float2 mlv = {m, l};
        *(float2*)&ML[(((size_t)(ks * HEADS + hh)) * N_TOK + q0 + ql) * 2] = mlv;
    }
}

// ---------------- combine split-K partials + inverse PRoPE -> f16 token-major ----------------
__global__ __launch_bounds__(256) void transform_out(const _Float16* __restrict__ OP,
                                                     const float* __restrict__ ML,
                                                     const float* __restrict__ mats,
                                                     _Float16* __restrict__ Ot) {
    const int T = blockIdx.x * 256 + threadIdx.x;
    const int sub = T & 7;
    const int h   = (T >> 3) & 15;
    const int n   = T >> 7;

    half8 op[KSPLIT];
    float2 ml[KSPLIT];
#pragma unroll
    for (int i = 0; i < KSPLIT; i++) {
        op[i] = *(const half8*)&OP[(((size_t)(i * HEADS + h)) * N_TOK + n) * HD + sub * 8];
        ml[i] = *(const float2*)&ML[(((size_t)(i * HEADS + h)) * N_TOK + n) * 2];
    }
    float mstar = ml[0].x;
#pragma unroll
    for (int i = 1; i < KSPLIT; i++) mstar = fmaxf(mstar, ml[i].x);
    float W = 0.0f;
    float t[8] = {0.f, 0.f, 0.f, 0.f, 0.f, 0.f, 0.f, 0.f};
#pragma unroll
    for (int i = 0; i < KSPLIT; i++) {
        const float wgt = __expf(ml[i].x - mstar) * ml[i].y;
        W += wgt;
#pragma unroll
        for (int d = 0; d < 8; d++) t[d] += wgt * (float)op[i][d];
    }
    const float rW = 1.0f / W;
#pragma unroll
    for (int d = 0; d < 8; d++) t[d] *= rW;

    const int cam = n >> 10;
    const float* A = mats + cam * 48 + 32;   // Ao = Pinv
    float r[8];
    if (sub < 4) {
#pragma unroll
        for (int g = 0; g < 2; g++)
#pragma unroll
            for (int i = 0; i < 4; i++)
                r[g*4+i] = A[i*4+0]*t[g*4+0] + A[i*4+1]*t[g*4+1]
                         + A[i*4+2]*t[g*4+2] + A[i*4+3]*t[g*4+3];
    } else {
        const int p = n & (NPER - 1);
        const float px = (float)(p & 31), py = (float)(p >> 5);
        const int pt0 = (sub - 4) * 4;
#pragma unroll
        for (int pp = 0; pp < 4; pp++) {
            const int pt = pt0 + pp;
            const float fr = __expf(-0.5756462732485114f * (float)(pt & 7));
            const float ang = (pt < NF ? px : py) * fr;
            float sn, cs; __sincosf(ang, &sn, &cs);
            const float a = t[pp*2], b = t[pp*2+1];
            r[pp*2]   = a * cs + b * sn;    // sign = -1
            r[pp*2+1] = -a * sn + b * cs;
        }
    }
    half8 o;
#pragma unroll
    for (int i = 0; i < 8; i++) o[i] = (_Float16)r[i];
    *(half8*)&Ot[(size_t)n * DIM + h * HD + sub * 8] = o;
}

// ---------------- launcher ----------------
extern "C" void kernel_launch(void* const* d_in, const int* in_sizes, int n_in,
                              void* d_out, int out_size, void* d_ws, size_t ws_size,
                              hipStream_t stream) {
    const float* x      = (const float*)d_in[0];
    const float* ext    = (const float*)d_in[1];
    const float* Ks     = (const float*)d_in[2];
    const float* qkv_w  = (const float*)d_in[3];
    const float* proj_w = (const float*)d_in[4];
    const float* proj_b = (const float*)d_in[5];
    float* out = (float*)d_out;

    float* ws   = (float*)d_ws;
    float* mats = ws + MATS_OFF;
    _Float16* Wprojf = (_Float16*)(ws + WPROJ_OFF);
    _Float16* Xf     = (_Float16*)(ws + XF_OFF);
    _Float16* Wqkvf  = (_Float16*)(ws + WQKV_OFF);
    _Float16* qkv16  = (_Float16*)(ws + QKV16_OFF);
    _Float16* OP     = (_Float16*)(ws + OP_OFF);
    float*    ML     = ws + ML_OFF;
    _Float16* Qf  = (_Float16*)(ws + Q_OFF);
    _Float16* Kf  = (_Float16*)(ws + K_OFF);
    _Float16* Vtf = (_Float16*)(ws + V_OFF);
    _Float16* Ot16 = (_Float16*)(ws + OT_OFF);

    build_mats<<<1, 64, 0, stream>>>(ext, Ks, mats);

    cast_inputs<<<3072, 256, 0, stream>>>(x, qkv_w, proj_w, Xf, Wqkvf, Wprojf);

    // qkv16 = x @ qkv_w^T : M=2048, Nn=3072, K=1024
    gemm_mfma<true><<<dim3(3*DIM/128, N_TOK/128), 256, 0, stream>>>(
        Xf, Wqkvf, nullptr, (void*)qkv16, 3*DIM, DIM);

    transform_qkv<<<N_TOK * 3 * HEADS * 8 / 256, 256, 0, stream>>>(qkv16, mats, Qf, Kf, Vtf);

    attn_mfma<<<KSPLIT * HEADS * (N_TOK / 64), 256, 0, stream>>>(Qf, Kf, Vtf, OP, ML);

    transform_out<<<N_TOK * HEADS * 8 / 256, 256, 0, stream>>>(OP, ML, mats, Ot16);

    // out = Ot @ proj_w^T + proj_b : M=2048, Nn=1024, K=1024
    gemm_mfma<false><<<dim3(DIM/128, N_TOK/128), 256, 0, stream>>>(
        Ot16, Wprojf, proj_b, (void*)out, DIM, DIM);
}

// Round 6
// 197.551 us; speedup vs baseline: 1.4176x; 1.4169x over previous
//
#include <hip/hip_runtime.h>
#include <math.h>

// ---------------- problem constants (fixed by reference file) ----------------
#define N_TOK   2048      // NC * PY * PX
#define DIM     1024
#define HEADS   16
#define HD      64        // head dim
#define NCAMS   2
#define NPER    1024      // tokens per camera (32*32)
#define DPROJ   32        // first half: projective 4x4 groups
#define NF      8         // rope freqs
#define KSPLIT  2         // attention key-dim split

typedef _Float16 half8  __attribute__((ext_vector_type(8)));
typedef _Float16 half4h __attribute__((ext_vector_type(4)));
typedef _Float16 half2h __attribute__((ext_vector_type(2)));
typedef float    floatx4 __attribute__((ext_vector_type(4)));

// ---------------- workspace layout (float-granular offsets) ----------------
#define MATS_OFF  0
#define WPROJ_OFF 256
#define SCR_OFF   (WPROJ_OFF + 524288)
#define XF_OFF    (SCR_OFF)                    // x f16: 2M halves = 1M fl
#define WQKV_OFF  (SCR_OFF + 1048576)          // qkv_w f16: 3M halves = 1.5M fl
#define QKV16_OFF (SCR_OFF + 2621440)          // qkv f16: 6M halves = 3M fl
#define OP_OFF    (SCR_OFF)                    // partial O f16 (reuses dead scratch)
#define ML_OFF    (SCR_OFF + 4194304)          // m,l f32
#define Q_OFF     (SCR_OFF + 5767168)          // f16 2M halves = 1M fl
#define K_OFF     (Q_OFF + 1048576)
#define V_OFF     (K_OFF + 1048576)
#define OT_OFF    (V_OFF + 1048576)            // f16 2M halves
// total ~= 10.5M floats ~= 40 MB

// ---------------- async global->LDS (16B per lane, wave-uniform LDS base) ----------------
__device__ __forceinline__ void gl_lds16(const void* g, void* s) {
    __builtin_amdgcn_global_load_lds((const __attribute__((address_space(1))) void*)g,
                                     (__attribute__((address_space(3))) void*)s, 16, 0, 0);
}

// ---------------- per-camera matrices ----------------
__global__ void build_mats(const float* __restrict__ ext, const float* __restrict__ Ks,
                           float* __restrict__ mats) {
    int c = threadIdx.x;
    if (c >= NCAMS) return;
    const float sx = 2.0f / 448.0f, sy = 2.0f / 448.0f;
    const float* Kc = Ks + c * 9;
    const float* E  = ext + c * 16;
    float Kn[16];
#pragma unroll
    for (int i = 0; i < 16; i++) Kn[i] = 0.0f;
    Kn[0]  = Kc[0] * sx;
    Kn[2]  = Kc[2] * sx - 1.0f;
    Kn[5]  = Kc[4] * sy;
    Kn[6]  = Kc[5] * sy - 1.0f;
    Kn[10] = 1.0f; Kn[15] = 1.0f;
    float P[16];
#pragma unroll
    for (int i = 0; i < 4; i++)
#pragma unroll
        for (int j = 0; j < 4; j++) {
            float s = 0.0f;
#pragma unroll
            for (int k = 0; k < 4; k++) s += Kn[i*4+k] * E[k*4+j];
            P[i*4+j] = s;
        }
    float M[4][8];
    for (int i = 0; i < 4; i++)
        for (int j = 0; j < 4; j++) { M[i][j] = P[i*4+j]; M[i][4+j] = (i==j) ? 1.0f : 0.0f; }
    for (int col = 0; col < 4; col++) {
        int piv = col;
        for (int r = col+1; r < 4; r++)
            if (fabsf(M[r][col]) > fabsf(M[piv][col])) piv = r;
        if (piv != col)
            for (int j = 0; j < 8; j++) { float tmp = M[col][j]; M[col][j] = M[piv][j]; M[piv][j] = tmp; }
        float d = 1.0f / M[col][col];
        for (int j = 0; j < 8; j++) M[col][j] *= d;
        for (int r = 0; r < 4; r++) {
            if (r == col) continue;
            float f = M[r][col];
            for (int j = 0; j < 8; j++) M[r][j] -= f * M[col][j];
        }
    }
    float Pi[16];
    for (int i = 0; i < 4; i++)
        for (int j = 0; j < 4; j++) Pi[i*4+j] = M[i][4+j];
    float* o = mats + c * 48;
    for (int i = 0; i < 4; i++)
        for (int j = 0; j < 4; j++) o[i*4+j] = Pi[j*4+i];   // Aq = Pinv^T
    for (int t = 0; t < 16; t++) o[16+t] = P[t];            // Ak = P
    for (int t = 0; t < 16; t++) o[32+t] = Pi[t];           // Ao = Pinv
}

// ---------------- cast x / qkv_w / proj_w to f16 ----------------
__global__ __launch_bounds__(256) void cast_inputs(const float* __restrict__ x,
                                                   const float* __restrict__ wqkv,
                                                   const float* __restrict__ wproj,
                                                   _Float16* __restrict__ xf,
                                                   _Float16* __restrict__ wqkvf,
                                                   _Float16* __restrict__ wprojf) {
    size_t i = ((size_t)blockIdx.x * 256 + threadIdx.x) * 8;
    const float* src; _Float16* dst; size_t off;
    if (i < (size_t)2*1024*1024)       { src = x;     dst = xf;     off = i; }
    else if (i < (size_t)5*1024*1024)  { src = wqkv;  dst = wqkvf;  off = i - (size_t)2*1024*1024; }
    else                               { src = wproj; dst = wprojf; off = i - (size_t)5*1024*1024; }
    float4 a = *(const float4*)(src + off);
    float4 b = *(const float4*)(src + off + 4);
    half8 h;
    h[0] = (_Float16)a.x; h[1] = (_Float16)a.y; h[2] = (_Float16)a.z; h[3] = (_Float16)a.w;
    h[4] = (_Float16)b.x; h[5] = (_Float16)b.y; h[6] = (_Float16)b.z; h[7] = (_Float16)b.w;
    *(half8*)(dst + off) = h;
}

// ---------------- MFMA f16 GEMM: C[M][Nn] = A[M][K] . B[Nn][K]^T ----------------
template <bool F16OUT>
__global__ __launch_bounds__(256) void gemm_mfma(const _Float16* __restrict__ A,
                                                 const _Float16* __restrict__ Bw,
                                                 const float* __restrict__ bias,
                                                 void* __restrict__ C,
                                                 int Nn, int Kd) {
    __shared__ _Float16 As[128 * 32];
    __shared__ _Float16 Bs[128 * 32];
    const int tid  = threadIdx.x;
    const int w    = tid >> 6, lane = tid & 63;
    const int ql   = lane & 15, quad = lane >> 4;
    const int lr   = lane >> 2, lc = lane & 3;
    const int wm   = w >> 1, wn = w & 1;
    const int row0 = blockIdx.y * 128, col0 = blockIdx.x * 128;

    floatx4 acc[4][4];
#pragma unroll
    for (int mt = 0; mt < 4; mt++)
#pragma unroll
        for (int nt = 0; nt < 4; nt++) acc[mt][nt] = (floatx4){0.f, 0.f, 0.f, 0.f};

    const _Float16* Ab = A  + (size_t)(row0 + w * 32 + lr) * Kd + lc * 8;
    const _Float16* Bb = Bw + (size_t)(col0 + w * 32 + lr) * Kd + lc * 8;
    _Float16* AsW = &As[(w * 32) * 32];
    _Float16* BsW = &Bs[(w * 32) * 32];

    for (int k0 = 0; k0 < Kd; k0 += 32) {
        gl_lds16(Ab + k0,            AsW);
        gl_lds16(Ab + 16 * Kd + k0,  AsW + 16 * 32);
        gl_lds16(Bb + k0,            BsW);
        gl_lds16(Bb + 16 * Kd + k0,  BsW + 16 * 32);
        __syncthreads();
        half8 af[4], bf[4];
#pragma unroll
        for (int mt = 0; mt < 4; mt++)
            af[mt] = *(const half8*)&As[(wm * 64 + mt * 16 + ql) * 32 + quad * 8];
#pragma unroll
        for (int nt = 0; nt < 4; nt++)
            bf[nt] = *(const half8*)&Bs[(wn * 64 + nt * 16 + ql) * 32 + quad * 8];
#pragma unroll
        for (int mt = 0; mt < 4; mt++)
#pragma unroll
            for (int nt = 0; nt < 4; nt++)
                acc[mt][nt] = __builtin_amdgcn_mfma_f32_16x16x32_f16(af[mt], bf[nt], acc[mt][nt], 0, 0, 0);
        __syncthreads();
    }

#pragma unroll
    for (int nt = 0; nt < 4; nt++) {
        const int col = col0 + wn * 64 + nt * 16 + ql;
        float bb = F16OUT ? 0.0f : bias[col];
#pragma unroll
        for (int mt = 0; mt < 4; mt++) {
            const int row = row0 + wm * 64 + mt * 16 + quad * 4;
            if (F16OUT) {
                _Float16* Cp = (_Float16*)C;
#pragma unroll
                for (int r = 0; r < 4; r++)
                    Cp[(size_t)(row + r) * Nn + col] = (_Float16)acc[mt][nt][r];
            } else {
                float* Cp = (float*)C;
#pragma unroll
                for (int r = 0; r < 4; r++)
                    Cp[(size_t)(row + r) * Nn + col] = acc[mt][nt][r] + bb;
            }
        }
    }
}

// ---------------- PRoPE transform: thread per 8 dims, no cross-lane ops ----------------
__global__ __launch_bounds__(256) void transform_qkv(const _Float16* __restrict__ qkv,
                                                     const float* __restrict__ mats,
                                                     _Float16* __restrict__ Qf,
                                                     _Float16* __restrict__ Kf,
                                                     _Float16* __restrict__ Vtf) {
    const int T = blockIdx.x * 256 + threadIdx.x;
    const int sub = T & 7;
    const int h   = (T >> 3) & 15;
    const int s   = (T >> 7) % 3;
    const int n   = T / 384;

    half8 v = *(const half8*)&qkv[(size_t)n * (3*DIM) + s * DIM + h * HD + sub * 8];
    float t[8];
#pragma unroll
    for (int i = 0; i < 8; i++) t[i] = (float)v[i];

    const int cam = n >> 10;
    const float* A = mats + cam * 48 + (s == 0 ? 0 : 16);
    float r[8];
    if (sub < 4) {
#pragma unroll
        for (int g = 0; g < 2; g++)
#pragma unroll
            for (int i = 0; i < 4; i++)
                r[g*4+i] = A[i*4+0]*t[g*4+0] + A[i*4+1]*t[g*4+1]
                         + A[i*4+2]*t[g*4+2] + A[i*4+3]*t[g*4+3];
    } else {
        const int p = n & (NPER - 1);
        const float px = (float)(p & 31), py = (float)(p >> 5);
        const int pt0 = (sub - 4) * 4;
#pragma unroll
        for (int pp = 0; pp < 4; pp++) {
            const int pt = pt0 + pp;
            const float fr = __expf(-0.5756462732485114f * (float)(pt & 7)); // 100^(-j/8)
            const float ang = (pt < NF ? px : py) * fr;
            float sn, cs; __sincosf(ang, &sn, &cs);
            const float a = t[pp*2], b = t[pp*2+1];
            r[pp*2]   = a * cs - b * sn;
            r[pp*2+1] = a * sn + b * cs;
        }
    }

    if (s == 0) {
        half8 o;
#pragma unroll
        for (int i = 0; i < 8; i++) o[i] = (_Float16)(r[i] * 0.125f);  // fold 1/sqrt(64)
        *(half8*)&Qf[((size_t)h * N_TOK + n) * HD + sub * 8] = o;
    } else if (s == 1) {
        half8 o;
#pragma unroll
        for (int i = 0; i < 8; i++) o[i] = (_Float16)r[i];
        *(half8*)&Kf[((size_t)h * N_TOK + n) * HD + sub * 8] = o;
    } else {
#pragma unroll
        for (int i = 0; i < 8; i++)
            Vtf[((size_t)h * HD + sub * 8 + i) * N_TOK + n] = (_Float16)r[i]; // [h][d][n]
    }
}

// ---------------- MFMA flash attention: LDS-staged K/V shared by all 4 waves ----------------
// Tiles staged via global_load_lds (contiguous 1KB per inst, 16 insts/block-iter vs 64).
// XOR chunk swizzle at stage time -> conflict-free ds_read_b128 fragment reads.
#define PLD 68
__global__ __launch_bounds__(256) void attn_mfma(const _Float16* __restrict__ Qh,
                                                 const _Float16* __restrict__ Kh,
                                                 const _Float16* __restrict__ Vt,
                                                 _Float16* __restrict__ OP,
                                                 float* __restrict__ ML) {
    __shared__ _Float16 sK[64 * 64];           // [key][dim], swizzled chunks
    __shared__ _Float16 sV[64 * 64];           // [dim][key], swizzled chunks
    __shared__ _Float16 P_lds[4][16][PLD];
    const int w    = threadIdx.x >> 6;
    const int lane = threadIdx.x & 63;
    const int b  = blockIdx.x;
    const int ks = b >> 9;
    const int hh = (b >> 5) & 15;
    const int qb = b & 31;
    const int ql = lane & 15, quad = lane >> 4;
    const int q0 = qb * 64 + w * 16;

    // staging lane roles: 8 rows x 8 chunks per instruction, XOR-swizzled chunk source
    const int srow = lane >> 3;                // 0..7
    const int schk = (lane & 7) ^ srow;        // global chunk this lane fetches
    // fragment-read chunk offsets (halves): stored-pos = wanted-chunk ^ (row&7)
    const int c0 = ((quad ^ (ql & 7)) << 3);   // dims/keys chunk `quad`
    const int c1 = c0 ^ 32;                    // chunk quad+4

    const _Float16* Qp = Qh + ((size_t)hh * N_TOK + q0 + ql) * HD;
    const half8 qf0 = *(const half8*)(Qp + quad * 8);
    const half8 qf1 = *(const half8*)(Qp + 32 + quad * 8);

    const _Float16* Kb = Kh + (size_t)hh * N_TOK * HD;
    const _Float16* Vb = Vt + (size_t)hh * HD * N_TOK;

    floatx4 O[4];
#pragma unroll
    for (int mt = 0; mt < 4; mt++) O[mt] = (floatx4){0.f, 0.f, 0.f, 0.f};
    float m = -1e30f, l = 0.0f;   // l lane-local, reduced after loop

    const int kstart = ks * (N_TOK / KSPLIT);
    const int kend   = kstart + (N_TOK / KSPLIT);

    for (int kb = kstart; kb < kend; kb += 64) {
        // ---- stage K and V tiles (each wave: 2+2 insts, 8 rows x 128B each) ----
#pragma unroll
        for (int j = 0; j < 2; j++) {
            const int r0 = w * 16 + j * 8;
            gl_lds16(Kb + (size_t)(kb + r0 + srow) * HD + schk * 8, &sK[r0 * 64]);
            gl_lds16(Vb + (size_t)(r0 + srow) * N_TOK + kb + schk * 8, &sV[r0 * 64]);
        }
        __syncthreads();
        // ---- S^T = K . Q^T from LDS fragments ----
        floatx4 s[4];
#pragma unroll
        for (int kt = 0; kt < 4; kt++) {
            const int rb = (kt * 16 + ql) * 64;
            half8 ka0 = *(const half8*)&sK[rb + c0];
            half8 ka1 = *(const half8*)&sK[rb + c1];
            floatx4 acc = (floatx4){0.f, 0.f, 0.f, 0.f};
            acc = __builtin_amdgcn_mfma_f32_16x16x32_f16(ka0, qf0, acc, 0, 0, 0);
            acc = __builtin_amdgcn_mfma_f32_16x16x32_f16(ka1, qf1, acc, 0, 0, 0);
            s[kt] = acc;
        }
        // ---- online softmax (2 cross-quad shuffles for m only) ----
        float bm = -1e30f;
#pragma unroll
        for (int kt = 0; kt < 4; kt++)
#pragma unroll
            for (int r = 0; r < 4; r++) bm = fmaxf(bm, s[kt][r]);
        bm = fmaxf(bm, __shfl_xor(bm, 16, 64));
        bm = fmaxf(bm, __shfl_xor(bm, 32, 64));
        const float mnew = fmaxf(m, bm);
        const float alpha = __expf(m - mnew);
        float p[4][4];
        float ps = 0.0f;
#pragma unroll
        for (int kt = 0; kt < 4; kt++)
#pragma unroll
            for (int r = 0; r < 4; r++) { p[kt][r] = __expf(s[kt][r] - mnew); ps += p[kt][r]; }
        l = l * alpha + ps;
        m = mnew;
#pragma unroll
        for (int mt = 0; mt < 4; mt++)
#pragma unroll
            for (int r = 0; r < 4; r++) O[mt][r] *= alpha;
        // ---- P -> per-wave LDS strip -> B-fragments ----
#pragma unroll
        for (int kt = 0; kt < 4; kt++) {
            half2h p01 = {(_Float16)p[kt][0], (_Float16)p[kt][1]};
            half2h p23 = {(_Float16)p[kt][2], (_Float16)p[kt][3]};
            *(half2h*)&P_lds[w][ql][kt * 16 + quad * 4]     = p01;
            *(half2h*)&P_lds[w][ql][kt * 16 + quad * 4 + 2] = p23;
        }
        half4h pa = *(const half4h*)&P_lds[w][ql][quad * 8];
        half4h pb = *(const half4h*)&P_lds[w][ql][quad * 8 + 4];
        half4h pc = *(const half4h*)&P_lds[w][ql][32 + quad * 8];
        half4h pd = *(const half4h*)&P_lds[w][ql][32 + quad * 8 + 4];
        half8 pf0, pf1;
#pragma unroll
        for (int j = 0; j < 4; j++) { pf0[j] = pa[j]; pf0[4 + j] = pb[j]; pf1[j] = pc[j]; pf1[4 + j] = pd[j]; }
        // ---- O^T += V^T . P from LDS fragments ----
#pragma unroll
        for (int mt = 0; mt < 4; mt++) {
            const int rb = (mt * 16 + ql) * 64;
            half8 va0 = *(const half8*)&sV[rb + c0];
            half8 va1 = *(const half8*)&sV[rb + c1];
            O[mt] = __builtin_amdgcn_mfma_f32_16x16x32_f16(va0, pf0, O[mt], 0, 0, 0);
            O[mt] = __builtin_amdgcn_mfma_f32_16x16x32_f16(va1, pf1, O[mt], 0, 0, 0);
        }
        __syncthreads();   // tiles consumed before next stage overwrites
    }
    // ---- final cross-quad l reduction ----
    l += __shfl_xor(l, 16, 64);
    l += __shfl_xor(l, 32, 64);
    const float rl = 1.0f / l;
    _Float16* Op = OP + (((size_t)(ks * HEADS + hh)) * N_TOK + q0 + ql) * HD;
#pragma unroll
    for (int mt = 0; mt < 4; mt++) {
        half4h o4;
#pragma unroll
        for (int r = 0; r < 4; r++) o4[r] = (_Float16)(O[mt][r] * rl);
        *(half4h*)&Op[mt * 16 + quad * 4] = o4;
    }
    if (quad == 0) {
        float2 mlv = {m, l};
        *(float2*)&ML[(((size_t)(ks * HEADS + hh)) * N_TOK + q0 + ql) * 2] = mlv;
    }
}

// ---------------- combine split-K partials + inverse PRoPE -> f16 token-major ----------------
__global__ __launch_bounds__(256) void transform_out(const _Float16* __restrict__ OP,
                                                     const float* __restrict__ ML,
                                                     const float* __restrict__ mats,
                                                     _Float16* __restrict__ Ot) {
    const int T = blockIdx.x * 256 + threadIdx.x;
    const int sub = T & 7;
    const int h   = (T >> 3) & 15;
    const int n   = T >> 7;

    half8 op[KSPLIT];
    float2 ml[KSPLIT];
#pragma unroll
    for (int i = 0; i < KSPLIT; i++) {
        op[i] = *(const half8*)&OP[(((size_t)(i * HEADS + h)) * N_TOK + n) * HD + sub * 8];
        ml[i] = *(const float2*)&ML[(((size_t)(i * HEADS + h)) * N_TOK + n) * 2];
    }
    float mstar = ml[0].x;
#pragma unroll
    for (int i = 1; i < KSPLIT; i++) mstar = fmaxf(mstar, ml[i].x);
    float W = 0.0f;
    float t[8] = {0.f, 0.f, 0.f, 0.f, 0.f, 0.f, 0.f, 0.f};
#pragma unroll
    for (int i = 0; i < KSPLIT; i++) {
        const float wgt = __expf(ml[i].x - mstar) * ml[i].y;
        W += wgt;
#pragma unroll
        for (int d = 0; d < 8; d++) t[d] += wgt * (float)op[i][d];
    }
    const float rW = 1.0f / W;
#pragma unroll
    for (int d = 0; d < 8; d++) t[d] *= rW;

    const int cam = n >> 10;
    const float* A = mats + cam * 48 + 32;   // Ao = Pinv
    float r[8];
    if (sub < 4) {
#pragma unroll
        for (int g = 0; g < 2; g++)
#pragma unroll
            for (int i = 0; i < 4; i++)
                r[g*4+i] = A[i*4+0]*t[g*4+0] + A[i*4+1]*t[g*4+1]
                         + A[i*4+2]*t[g*4+2] + A[i*4+3]*t[g*4+3];
    } else {
        const int p = n & (NPER - 1);
        const float px = (float)(p & 31), py = (float)(p >> 5);
        const int pt0 = (sub - 4) * 4;
#pragma unroll
        for (int pp = 0; pp < 4; pp++) {
            const int pt = pt0 + pp;
            const float fr = __expf(-0.5756462732485114f * (float)(pt & 7));
            const float ang = (pt < NF ? px : py) * fr;
            float sn, cs; __sincosf(ang, &sn, &cs);
            const float a = t[pp*2], b = t[pp*2+1];
            r[pp*2]   = a * cs + b * sn;    // sign = -1
            r[pp*2+1] = -a * sn + b * cs;
        }
    }
    half8 o;
#pragma unroll
    for (int i = 0; i < 8; i++) o[i] = (_Float16)r[i];
    *(half8*)&Ot[(size_t)n * DIM + h * HD + sub * 8] = o;
}

// ---------------- launcher ----------------
extern "C" void kernel_launch(void* const* d_in, const int* in_sizes, int n_in,
                              void* d_out, int out_size, void* d_ws, size_t ws_size,
                              hipStream_t stream) {
    const float* x      = (const float*)d_in[0];
    const float* ext    = (const float*)d_in[1];
    const float* Ks     = (const float*)d_in[2];
    const float* qkv_w  = (const float*)d_in[3];
    const float* proj_w = (const float*)d_in[4];
    const float* proj_b = (const float*)d_in[5];
    float* out = (float*)d_out;

    float* ws   = (float*)d_ws;
    float* mats = ws + MATS_OFF;
    _Float16* Wprojf = (_Float16*)(ws + WPROJ_OFF);
    _Float16* Xf     = (_Float16*)(ws + XF_OFF);
    _Float16* Wqkvf  = (_Float16*)(ws + WQKV_OFF);
    _Float16* qkv16  = (_Float16*)(ws + QKV16_OFF);
    _Float16* OP     = (_Float16*)(ws + OP_OFF);
    float*    ML     = ws + ML_OFF;
    _Float16* Qf  = (_Float16*)(ws + Q_OFF);
    _Float16* Kf  = (_Float16*)(ws + K_OFF);
    _Float16* Vtf = (_Float16*)(ws + V_OFF);
    _Float16* Ot16 = (_Float16*)(ws + OT_OFF);

    build_mats<<<1, 64, 0, stream>>>(ext, Ks, mats);

    cast_inputs<<<3072, 256, 0, stream>>>(x, qkv_w, proj_w, Xf, Wqkvf, Wprojf);

    // qkv16 = x @ qkv_w^T : M=2048, Nn=3072, K=1024
    gemm_mfma<true><<<dim3(3*DIM/128, N_TOK/128), 256, 0, stream>>>(
        Xf, Wqkvf, nullptr, (void*)qkv16, 3*DIM, DIM);

    transform_qkv<<<N_TOK * 3 * HEADS * 8 / 256, 256, 0, stream>>>(qkv16, mats, Qf, Kf, Vtf);

    attn_mfma<<<KSPLIT * HEADS * (N_TOK / 64), 256, 0, stream>>>(Qf, Kf, Vtf, OP, ML);

    transform_out<<<N_TOK * HEADS * 8 / 256, 256, 0, stream>>>(OP, ML, mats, Ot16);

    // out = Ot @ proj_w^T + proj_b : M=2048, Nn=1024, K=1024
    gemm_mfma<false><<<dim3(DIM/128, N_TOK/128), 256, 0, stream>>>(
        Ot16, Wprojf, proj_b, (void*)out, DIM, DIM);
}

// Round 7
// 194.253 us; speedup vs baseline: 1.4417x; 1.0170x over previous
//
#include <hip/hip_runtime.h>
#include <math.h>

// ---------------- problem constants (fixed by reference file) ----------------
#define N_TOK   2048      // NC * PY * PX
#define DIM     1024
#define HEADS   16
#define HD      64        // head dim
#define NCAMS   2
#define NPER    1024      // tokens per camera (32*32)
#define DPROJ   32        // first half: projective 4x4 groups
#define NF      8         // rope freqs
#define KSPLIT  2         // attention key-dim split

typedef _Float16 half8  __attribute__((ext_vector_type(8)));
typedef _Float16 half4h __attribute__((ext_vector_type(4)));
typedef _Float16 half2h __attribute__((ext_vector_type(2)));
typedef float    floatx4 __attribute__((ext_vector_type(4)));

// ---------------- workspace layout (float-granular offsets) ----------------
#define MATS_OFF  0
#define WPROJ_OFF 256
#define SCR_OFF   (WPROJ_OFF + 524288)
#define XF_OFF    (SCR_OFF)                    // x f16: 2M halves = 1M fl
#define WQKV_OFF  (SCR_OFF + 1048576)          // qkv_w f16: 3M halves = 1.5M fl
#define QKV16_OFF (SCR_OFF + 2621440)          // qkv f16: 6M halves = 3M fl
#define OP_OFF    (SCR_OFF)                    // partial O f16 (reuses dead scratch)
#define ML_OFF    (SCR_OFF + 4194304)          // m,l f32
#define Q_OFF     (SCR_OFF + 5767168)          // f16 2M halves = 1M fl
#define K_OFF     (Q_OFF + 1048576)
#define V_OFF     (K_OFF + 1048576)
#define OT_OFF    (V_OFF + 1048576)            // f16 2M halves
// total ~= 10.5M floats ~= 40 MB

// ---------------- async global->LDS (16B per lane, wave-uniform LDS base) ----------------
__device__ __forceinline__ void gl_lds16(const void* g, void* s) {
    __builtin_amdgcn_global_load_lds((const __attribute__((address_space(1))) void*)g,
                                     (__attribute__((address_space(3))) void*)s, 16, 0, 0);
}

// ---------------- per-camera matrices ----------------
__global__ void build_mats(const float* __restrict__ ext, const float* __restrict__ Ks,
                           float* __restrict__ mats) {
    int c = threadIdx.x;
    if (c >= NCAMS) return;
    const float sx = 2.0f / 448.0f, sy = 2.0f / 448.0f;
    const float* Kc = Ks + c * 9;
    const float* E  = ext + c * 16;
    float Kn[16];
#pragma unroll
    for (int i = 0; i < 16; i++) Kn[i] = 0.0f;
    Kn[0]  = Kc[0] * sx;
    Kn[2]  = Kc[2] * sx - 1.0f;
    Kn[5]  = Kc[4] * sy;
    Kn[6]  = Kc[5] * sy - 1.0f;
    Kn[10] = 1.0f; Kn[15] = 1.0f;
    float P[16];
#pragma unroll
    for (int i = 0; i < 4; i++)
#pragma unroll
        for (int j = 0; j < 4; j++) {
            float s = 0.0f;
#pragma unroll
            for (int k = 0; k < 4; k++) s += Kn[i*4+k] * E[k*4+j];
            P[i*4+j] = s;
        }
    float M[4][8];
    for (int i = 0; i < 4; i++)
        for (int j = 0; j < 4; j++) { M[i][j] = P[i*4+j]; M[i][4+j] = (i==j) ? 1.0f : 0.0f; }
    for (int col = 0; col < 4; col++) {
        int piv = col;
        for (int r = col+1; r < 4; r++)
            if (fabsf(M[r][col]) > fabsf(M[piv][col])) piv = r;
        if (piv != col)
            for (int j = 0; j < 8; j++) { float tmp = M[col][j]; M[col][j] = M[piv][j]; M[piv][j] = tmp; }
        float d = 1.0f / M[col][col];
        for (int j = 0; j < 8; j++) M[col][j] *= d;
        for (int r = 0; r < 4; r++) {
            if (r == col) continue;
            float f = M[r][col];
            for (int j = 0; j < 8; j++) M[r][j] -= f * M[col][j];
        }
    }
    float Pi[16];
    for (int i = 0; i < 4; i++)
        for (int j = 0; j < 4; j++) Pi[i*4+j] = M[i][4+j];
    float* o = mats + c * 48;
    for (int i = 0; i < 4; i++)
        for (int j = 0; j < 4; j++) o[i*4+j] = Pi[j*4+i];   // Aq = Pinv^T
    for (int t = 0; t < 16; t++) o[16+t] = P[t];            // Ak = P
    for (int t = 0; t < 16; t++) o[32+t] = Pi[t];           // Ao = Pinv
}

// ---------------- cast x / qkv_w / proj_w to f16 ----------------
__global__ __launch_bounds__(256) void cast_inputs(const float* __restrict__ x,
                                                   const float* __restrict__ wqkv,
                                                   const float* __restrict__ wproj,
                                                   _Float16* __restrict__ xf,
                                                   _Float16* __restrict__ wqkvf,
                                                   _Float16* __restrict__ wprojf) {
    size_t i = ((size_t)blockIdx.x * 256 + threadIdx.x) * 8;
    const float* src; _Float16* dst; size_t off;
    if (i < (size_t)2*1024*1024)       { src = x;     dst = xf;     off = i; }
    else if (i < (size_t)5*1024*1024)  { src = wqkv;  dst = wqkvf;  off = i - (size_t)2*1024*1024; }
    else                               { src = wproj; dst = wprojf; off = i - (size_t)5*1024*1024; }
    float4 a = *(const float4*)(src + off);
    float4 b = *(const float4*)(src + off + 4);
    half8 h;
    h[0] = (_Float16)a.x; h[1] = (_Float16)a.y; h[2] = (_Float16)a.z; h[3] = (_Float16)a.w;
    h[4] = (_Float16)b.x; h[5] = (_Float16)b.y; h[6] = (_Float16)b.z; h[7] = (_Float16)b.w;
    *(half8*)(dst + off) = h;
}

// ---------------- MFMA f16 GEMM: C[M][Nn] = A[M][K] . B[Nn][K]^T ----------------
// 64x128 tile, BK=32, double-buffered LDS, single barrier per K-step.
// 4 waves: wave w computes rows 0..63 x cols w*32..w*32+31 (acc 4x2 of 16x16x32).
template <bool F16OUT>
__global__ __launch_bounds__(256) void gemm_mfma(const _Float16* __restrict__ A,
                                                 const _Float16* __restrict__ Bw,
                                                 const float* __restrict__ bias,
                                                 void* __restrict__ C,
                                                 int Nn, int Kd) {
    __shared__ _Float16 As[2][64 * 32];
    __shared__ _Float16 Bs[2][128 * 32];
    const int tid  = threadIdx.x;
    const int w    = tid >> 6, lane = tid & 63;
    const int ql   = lane & 15, quad = lane >> 4;
    const int lr   = lane >> 2, lc = lane & 3;        // staging: row-in-16, 16B chunk
    const int row0 = blockIdx.y * 64, col0 = blockIdx.x * 128;

    floatx4 acc[4][2];
#pragma unroll
    for (int mt = 0; mt < 4; mt++)
#pragma unroll
        for (int nt = 0; nt < 2; nt++) acc[mt][nt] = (floatx4){0.f, 0.f, 0.f, 0.f};

    // staging base pointers (wave w: A rows w*16.., B rows w*32.. and w*32+16..)
    const _Float16* Ab  = A  + (size_t)(row0 + w * 16 + lr) * Kd + lc * 8;
    const _Float16* Bb0 = Bw + (size_t)(col0 + w * 32 + lr) * Kd + lc * 8;
    const _Float16* Bb1 = Bw + (size_t)(col0 + w * 32 + 16 + lr) * Kd + lc * 8;

    // prologue: stage k0=0 into buf 0
    gl_lds16(Ab,  &As[0][(w * 16) * 32]);
    gl_lds16(Bb0, &Bs[0][(w * 32) * 32]);
    gl_lds16(Bb1, &Bs[0][(w * 32 + 16) * 32]);

    const int nIter = Kd >> 5;
    for (int i = 0; i < nIter; i++) {
        __syncthreads();                 // buf[i&1] staged; prior reads of buf[(i+1)&1] done
        if (i + 1 < nIter) {
            const int k0 = (i + 1) << 5;
            const int nb = (i + 1) & 1;
            gl_lds16(Ab + k0,  &As[nb][(w * 16) * 32]);
            gl_lds16(Bb0 + k0, &Bs[nb][(w * 32) * 32]);
            gl_lds16(Bb1 + k0, &Bs[nb][(w * 32 + 16) * 32]);
        }
        const int cur = i & 1;
        half8 af[4], bf[2];
#pragma unroll
        for (int mt = 0; mt < 4; mt++)
            af[mt] = *(const half8*)&As[cur][(mt * 16 + ql) * 32 + quad * 8];
#pragma unroll
        for (int nt = 0; nt < 2; nt++)
            bf[nt] = *(const half8*)&Bs[cur][(w * 32 + nt * 16 + ql) * 32 + quad * 8];
#pragma unroll
        for (int mt = 0; mt < 4; mt++)
#pragma unroll
            for (int nt = 0; nt < 2; nt++)
                acc[mt][nt] = __builtin_amdgcn_mfma_f32_16x16x32_f16(af[mt], bf[nt], acc[mt][nt], 0, 0, 0);
    }

#pragma unroll
    for (int nt = 0; nt < 2; nt++) {
        const int col = col0 + w * 32 + nt * 16 + ql;
        float bb = F16OUT ? 0.0f : bias[col];
#pragma unroll
        for (int mt = 0; mt < 4; mt++) {
            const int row = row0 + mt * 16 + quad * 4;
            if (F16OUT) {
                _Float16* Cp = (_Float16*)C;
#pragma unroll
                for (int r = 0; r < 4; r++)
                    Cp[(size_t)(row + r) * Nn + col] = (_Float16)acc[mt][nt][r];
            } else {
                float* Cp = (float*)C;
#pragma unroll
                for (int r = 0; r < 4; r++)
                    Cp[(size_t)(row + r) * Nn + col] = acc[mt][nt][r] + bb;
            }
        }
    }
}

// ---------------- PRoPE transform for Q and K (coalesced both ways) ----------------
// T = ((n*2 + s)*16 + h)*8 + sub
__global__ __launch_bounds__(256) void transform_qk(const _Float16* __restrict__ qkv,
                                                    const float* __restrict__ mats,
                                                    _Float16* __restrict__ Qf,
                                                    _Float16* __restrict__ Kf) {
    const int T = blockIdx.x * 256 + threadIdx.x;
    const int sub = T & 7;
    const int h   = (T >> 3) & 15;
    const int s   = (T >> 7) & 1;
    const int n   = T >> 8;

    half8 v = *(const half8*)&qkv[(size_t)n * (3*DIM) + s * DIM + h * HD + sub * 8];
    float t[8];
#pragma unroll
    for (int i = 0; i < 8; i++) t[i] = (float)v[i];

    const int cam = n >> 10;
    const float* A = mats + cam * 48 + (s == 0 ? 0 : 16);
    float r[8];
    if (sub < 4) {
#pragma unroll
        for (int g = 0; g < 2; g++)
#pragma unroll
            for (int i = 0; i < 4; i++)
                r[g*4+i] = A[i*4+0]*t[g*4+0] + A[i*4+1]*t[g*4+1]
                         + A[i*4+2]*t[g*4+2] + A[i*4+3]*t[g*4+3];
    } else {
        const int p = n & (NPER - 1);
        const float px = (float)(p & 31), py = (float)(p >> 5);
        const int pt0 = (sub - 4) * 4;
#pragma unroll
        for (int pp = 0; pp < 4; pp++) {
            const int pt = pt0 + pp;
            const float fr = __expf(-0.5756462732485114f * (float)(pt & 7)); // 100^(-j/8)
            const float ang = (pt < NF ? px : py) * fr;
            float sn, cs; __sincosf(ang, &sn, &cs);
            const float a = t[pp*2], b = t[pp*2+1];
            r[pp*2]   = a * cs - b * sn;
            r[pp*2+1] = a * sn + b * cs;
        }
    }

    if (s == 0) {
        half8 o;
#pragma unroll
        for (int i = 0; i < 8; i++) o[i] = (_Float16)(r[i] * 0.125f);  // fold 1/sqrt(64)
        *(half8*)&Qf[((size_t)h * N_TOK + n) * HD + sub * 8] = o;
    } else {
        half8 o;
#pragma unroll
        for (int i = 0; i < 8; i++) o[i] = (_Float16)r[i];
        *(half8*)&Kf[((size_t)h * N_TOK + n) * HD + sub * 8] = o;
    }
}

// ---------------- PRoPE transform for V -> transposed [h][d][n], coalesced stores ----------
// u: bits [5:0]=n_low (lane), [8:6]=sub, [12:9]=h, [17:13]=n_high
__global__ __launch_bounds__(256) void transform_v(const _Float16* __restrict__ qkv,
                                                   const float* __restrict__ mats,
                                                   _Float16* __restrict__ Vtf) {
    const int u   = blockIdx.x * 256 + threadIdx.x;
    const int nl  = u & 63;
    const int sub = (u >> 6) & 7;
    const int h   = (u >> 9) & 15;
    const int nh  = u >> 13;
    const int n   = nh * 64 + nl;

    half8 v = *(const half8*)&qkv[(size_t)n * (3*DIM) + 2 * DIM + h * HD + sub * 8];
    float t[8];
#pragma unroll
    for (int i = 0; i < 8; i++) t[i] = (float)v[i];

    const int cam = n >> 10;
    const float* A = mats + cam * 48 + 16;   // Ak = P (v uses same transform as k)
    float r[8];
    if (sub < 4) {
#pragma unroll
        for (int g = 0; g < 2; g++)
#pragma unroll
            for (int i = 0; i < 4; i++)
                r[g*4+i] = A[i*4+0]*t[g*4+0] + A[i*4+1]*t[g*4+1]
                         + A[i*4+2]*t[g*4+2] + A[i*4+3]*t[g*4+3];
    } else {
        const int p = n & (NPER - 1);
        const float px = (float)(p & 31), py = (float)(p >> 5);
        const int pt0 = (sub - 4) * 4;
#pragma unroll
        for (int pp = 0; pp < 4; pp++) {
            const int pt = pt0 + pp;
            const float fr = __expf(-0.5756462732485114f * (float)(pt & 7));
            const float ang = (pt < NF ? px : py) * fr;
            float sn, cs; __sincosf(ang, &sn, &cs);
            const float a = t[pp*2], b = t[pp*2+1];
            r[pp*2]   = a * cs - b * sn;
            r[pp*2+1] = a * sn + b * cs;
        }
    }
#pragma unroll
    for (int i = 0; i < 8; i++)
        Vtf[(size_t)(h * HD + sub * 8 + i) * N_TOK + n] = (_Float16)r[i];  // lane-coalesced
}

// ---------------- MFMA flash attention: dbuf LDS K/V, single barrier per tile ------------
#define PLD 68
__global__ __launch_bounds__(256) void attn_mfma(const _Float16* __restrict__ Qh,
                                                 const _Float16* __restrict__ Kh,
                                                 const _Float16* __restrict__ Vt,
                                                 _Float16* __restrict__ OP,
                                                 float* __restrict__ ML) {
    __shared__ _Float16 sK[2][64 * 64];        // [key][dim], swizzled chunks
    __shared__ _Float16 sV[2][64 * 64];        // [dim][key], swizzled chunks
    __shared__ _Float16 P_lds[4][16][PLD];
    const int w    = threadIdx.x >> 6;
    const int lane = threadIdx.x & 63;
    const int b  = blockIdx.x;
    const int ks = b >> 9;
    const int hh = (b >> 5) & 15;
    const int qb = b & 31;
    const int ql = lane & 15, quad = lane >> 4;
    const int q0 = qb * 64 + w * 16;

    const int srow = lane >> 3;                // staging: row-in-8
    const int schk = (lane & 7) ^ srow;        // XOR-swizzled chunk
    const int c0 = ((quad ^ (ql & 7)) << 3);   // reader: chunk quad
    const int c1 = c0 ^ 32;                    // chunk quad+4

    const _Float16* Qp = Qh + ((size_t)hh * N_TOK + q0 + ql) * HD;
    const half8 qf0 = *(const half8*)(Qp + quad * 8);
    const half8 qf1 = *(const half8*)(Qp + 32 + quad * 8);

    const _Float16* Kb = Kh + (size_t)hh * N_TOK * HD;
    const _Float16* Vb = Vt + (size_t)hh * HD * N_TOK;

    floatx4 O[4];
#pragma unroll
    for (int mt = 0; mt < 4; mt++) O[mt] = (floatx4){0.f, 0.f, 0.f, 0.f};
    float m = -1e30f, l = 0.0f;   // l lane-local, reduced after loop

    const int kstart = ks * (N_TOK / KSPLIT);
    const int nIter  = (N_TOK / KSPLIT) / 64;

    // prologue: stage tile 0 into buf 0
#pragma unroll
    for (int j = 0; j < 2; j++) {
        const int r0 = w * 16 + j * 8;
        gl_lds16(Kb + (size_t)(kstart + r0 + srow) * HD + schk * 8, &sK[0][r0 * 64]);
        gl_lds16(Vb + (size_t)(r0 + srow) * N_TOK + kstart + schk * 8, &sV[0][r0 * 64]);
    }

    for (int i = 0; i < nIter; i++) {
        __syncthreads();               // buf[i&1] staged; buf[(i+1)&1] reads (iter i-1) done
        if (i + 1 < nIter) {
            const int kbn = kstart + (i + 1) * 64;
            const int nb  = (i + 1) & 1;
#pragma unroll
            for (int j = 0; j < 2; j++) {
                const int r0 = w * 16 + j * 8;
                gl_lds16(Kb + (size_t)(kbn + r0 + srow) * HD + schk * 8, &sK[nb][r0 * 64]);
                gl_lds16(Vb + (size_t)(r0 + srow) * N_TOK + kbn + schk * 8, &sV[nb][r0 * 64]);
            }
        }
        const int cur = i & 1;
        // ---- S^T = K . Q^T from LDS fragments ----
        floatx4 s[4];
#pragma unroll
        for (int kt = 0; kt < 4; kt++) {
            const int rb = (kt * 16 + ql) * 64;
            half8 ka0 = *(const half8*)&sK[cur][rb + c0];
            half8 ka1 = *(const half8*)&sK[cur][rb + c1];
            floatx4 acc = (floatx4){0.f, 0.f, 0.f, 0.f};
            acc = __builtin_amdgcn_mfma_f32_16x16x32_f16(ka0, qf0, acc, 0, 0, 0);
            acc = __builtin_amdgcn_mfma_f32_16x16x32_f16(ka1, qf1, acc, 0, 0, 0);
            s[kt] = acc;
        }
        // ---- online softmax (2 cross-quad shuffles for m only) ----
        float bm = -1e30f;
#pragma unroll
        for (int kt = 0; kt < 4; kt++)
#pragma unroll
            for (int r = 0; r < 4; r++) bm = fmaxf(bm, s[kt][r]);
        bm = fmaxf(bm, __shfl_xor(bm, 16, 64));
        bm = fmaxf(bm, __shfl_xor(bm, 32, 64));
        const float mnew = fmaxf(m, bm);
        const float alpha = __expf(m - mnew);
        float p[4][4];
        float ps = 0.0f;
#pragma unroll
        for (int kt = 0; kt < 4; kt++)
#pragma unroll
            for (int r = 0; r < 4; r++) { p[kt][r] = __expf(s[kt][r] - mnew); ps += p[kt][r]; }
        l = l * alpha + ps;
        m = mnew;
#pragma unroll
        for (int mt = 0; mt < 4; mt++)
#pragma unroll
            for (int r = 0; r < 4; r++) O[mt][r] *= alpha;
        // ---- P -> per-wave LDS strip -> B-fragments ----
#pragma unroll
        for (int kt = 0; kt < 4; kt++) {
            half2h p01 = {(_Float16)p[kt][0], (_Float16)p[kt][1]};
            half2h p23 = {(_Float16)p[kt][2], (_Float16)p[kt][3]};
            *(half2h*)&P_lds[w][ql][kt * 16 + quad * 4]     = p01;
            *(half2h*)&P_lds[w][ql][kt * 16 + quad * 4 + 2] = p23;
        }
        half4h pa = *(const half4h*)&P_lds[w][ql][quad * 8];
        half4h pb = *(const half4h*)&P_lds[w][ql][quad * 8 + 4];
        half4h pc = *(const half4h*)&P_lds[w][ql][32 + quad * 8];
        half4h pd = *(const half4h*)&P_lds[w][ql][32 + quad * 8 + 4];
        half8 pf0, pf1;
#pragma unroll
        for (int j = 0; j < 4; j++) { pf0[j] = pa[j]; pf0[4 + j] = pb[j]; pf1[j] = pc[j]; pf1[4 + j] = pd[j]; }
        // ---- O^T += V^T . P from LDS fragments ----
#pragma unroll
        for (int mt = 0; mt < 4; mt++) {
            const int rb = (mt * 16 + ql) * 64;
            half8 va0 = *(const half8*)&sV[cur][rb + c0];
            half8 va1 = *(const half8*)&sV[cur][rb + c1];
            O[mt] = __builtin_amdgcn_mfma_f32_16x16x32_f16(va0, pf0, O[mt], 0, 0, 0);
            O[mt] = __builtin_amdgcn_mfma_f32_16x16x32_f16(va1, pf1, O[mt], 0, 0, 0);
        }
    }
    // ---- final cross-quad l reduction ----
    l += __shfl_xor(l, 16, 64);
    l += __shfl_xor(l, 32, 64);
    const float rl = 1.0f / l;
    _Float16* Op = OP + (((size_t)(ks * HEADS + hh)) * N_TOK + q0 + ql) * HD;
#pragma unroll
    for (int mt = 0; mt < 4; mt++) {
        half4h o4;
#pragma unroll
        for (int r = 0; r < 4; r++) o4[r] = (_Float16)(O[mt][r] * rl);
        *(half4h*)&Op[mt * 16 + quad * 4] = o4;
    }
    if (quad == 0) {
        float2 mlv = {m, l};
        *(float2*)&ML[(((size_t)(ks * HEADS + hh)) * N_TOK + q0 + ql) * 2] = mlv;
    }
}

// ---------------- combine split-K partials + inverse PRoPE -> f16 token-major ----------------
__global__ __launch_bounds__(256) void transform_out(const _Float16* __restrict__ OP,
                                                     const float* __restrict__ ML,
                                                     const float* __restrict__ mats,
                                                     _Float16* __restrict__ Ot) {
    const int T = blockIdx.x * 256 + threadIdx.x;
    const int sub = T & 7;
    const int h   = (T >> 3) & 15;
    const int n   = T >> 7;

    half8 op[KSPLIT];
    float2 ml[KSPLIT];
#pragma unroll
    for (int i = 0; i < KSPLIT; i++) {
        op[i] = *(const half8*)&OP[(((size_t)(i * HEADS + h)) * N_TOK + n) * HD + sub * 8];
        ml[i] = *(const float2*)&ML[(((size_t)(i * HEADS + h)) * N_TOK + n) * 2];
    }
    float mstar = ml[0].x;
#pragma unroll
    for (int i = 1; i < KSPLIT; i++) mstar = fmaxf(mstar, ml[i].x);
    float W = 0.0f;
    float t[8] = {0.f, 0.f, 0.f, 0.f, 0.f, 0.f, 0.f, 0.f};
#pragma unroll
    for (int i = 0; i < KSPLIT; i++) {
        const float wgt = __expf(ml[i].x - mstar) * ml[i].y;
        W += wgt;
#pragma unroll
        for (int d = 0; d < 8; d++) t[d] += wgt * (float)op[i][d];
    }
    const float rW = 1.0f / W;
#pragma unroll
    for (int d = 0; d < 8; d++) t[d] *= rW;

    const int cam = n >> 10;
    const float* A = mats + cam * 48 + 32;   // Ao = Pinv
    float r[8];
    if (sub < 4) {
#pragma unroll
        for (int g = 0; g < 2; g++)
#pragma unroll
            for (int i = 0; i < 4; i++)
                r[g*4+i] = A[i*4+0]*t[g*4+0] + A[i*4+1]*t[g*4+1]
                         + A[i*4+2]*t[g*4+2] + A[i*4+3]*t[g*4+3];
    } else {
        const int p = n & (NPER - 1);
        const float px = (float)(p & 31), py = (float)(p >> 5);
        const int pt0 = (sub - 4) * 4;
#pragma unroll
        for (int pp = 0; pp < 4; pp++) {
            const int pt = pt0 + pp;
            const float fr = __expf(-0.5756462732485114f * (float)(pt & 7));
            const float ang = (pt < NF ? px : py) * fr;
            float sn, cs; __sincosf(ang, &sn, &cs);
            const float a = t[pp*2], b = t[pp*2+1];
            r[pp*2]   = a * cs + b * sn;    // sign = -1
            r[pp*2+1] = -a * sn + b * cs;
        }
    }
    half8 o;
#pragma unroll
    for (int i = 0; i < 8; i++) o[i] = (_Float16)r[i];
    *(half8*)&Ot[(size_t)n * DIM + h * HD + sub * 8] = o;
}

// ---------------- launcher ----------------
extern "C" void kernel_launch(void* const* d_in, const int* in_sizes, int n_in,
                              void* d_out, int out_size, void* d_ws, size_t ws_size,
                              hipStream_t stream) {
    const float* x      = (const float*)d_in[0];
    const float* ext    = (const float*)d_in[1];
    const float* Ks     = (const float*)d_in[2];
    const float* qkv_w  = (const float*)d_in[3];
    const float* proj_w = (const float*)d_in[4];
    const float* proj_b = (const float*)d_in[5];
    float* out = (float*)d_out;

    float* ws   = (float*)d_ws;
    float* mats = ws + MATS_OFF;
    _Float16* Wprojf = (_Float16*)(ws + WPROJ_OFF);
    _Float16* Xf     = (_Float16*)(ws + XF_OFF);
    _Float16* Wqkvf  = (_Float16*)(ws + WQKV_OFF);
    _Float16* qkv16  = (_Float16*)(ws + QKV16_OFF);
    _Float16* OP     = (_Float16*)(ws + OP_OFF);
    float*    ML     = ws + ML_OFF;
    _Float16* Qf  = (_Float16*)(ws + Q_OFF);
    _Float16* Kf  = (_Float16*)(ws + K_OFF);
    _Float16* Vtf = (_Float16*)(ws + V_OFF);
    _Float16* Ot16 = (_Float16*)(ws + OT_OFF);

    build_mats<<<1, 64, 0, stream>>>(ext, Ks, mats);

    cast_inputs<<<3072, 256, 0, stream>>>(x, qkv_w, proj_w, Xf, Wqkvf, Wprojf);

    // qkv16 = x @ qkv_w^T : M=2048, Nn=3072, K=1024  (768 blocks = 3/CU)
    gemm_mfma<true><<<dim3(3*DIM/128, N_TOK/64), 256, 0, stream>>>(
        Xf, Wqkvf, nullptr, (void*)qkv16, 3*DIM, DIM);

    transform_qk<<<N_TOK * 2 * HEADS * 8 / 256, 256, 0, stream>>>(qkv16, mats, Qf, Kf);
    transform_v<<<N_TOK * HEADS * 8 / 256, 256, 0, stream>>>(qkv16, mats, Vtf);

    attn_mfma<<<KSPLIT * HEADS * (N_TOK / 64), 256, 0, stream>>>(Qf, Kf, Vtf, OP, ML);

    transform_out<<<N_TOK * HEADS * 8 / 256, 256, 0, stream>>>(OP, ML, mats, Ot16);

    // out = Ot @ proj_w^T + proj_b : M=2048, Nn=1024, K=1024  (256 blocks = 1/CU)
    gemm_mfma<false><<<dim3(DIM/128, N_TOK/64), 256, 0, stream>>>(
        Ot16, Wprojf, proj_b, (void*)out, DIM, DIM);
}

// Round 9
// 183.094 us; speedup vs baseline: 1.5296x; 1.0609x over previous
//
#include <hip/hip_runtime.h>
#include <math.h>

// ---------------- problem constants (fixed by reference file) ----------------
#define N_TOK   2048      // NC * PY * PX
#define DIM     1024
#define HEADS   16
#define HD      64        // head dim
#define NCAMS   2
#define NPER    1024      // tokens per camera (32*32)
#define DPROJ   32        // first half: projective 4x4 groups
#define NF      8         // rope freqs
#define KSPLIT  4         // attention key-dim split

#define LOG2E   1.44269504088896340736f

typedef _Float16 half8  __attribute__((ext_vector_type(8)));
typedef _Float16 half4h __attribute__((ext_vector_type(4)));
typedef _Float16 half2h __attribute__((ext_vector_type(2)));
typedef __fp16   fp16x2 __attribute__((ext_vector_type(2)));   // native type of cvt_pkrtz
typedef float    floatx4 __attribute__((ext_vector_type(4)));

// ---------------- workspace layout (float-granular offsets) ----------------
#define MATS_OFF  0
#define WPROJ_OFF 256
#define SCR_OFF   (WPROJ_OFF + 524288)
#define XF_OFF    (SCR_OFF)                    // x f16: 2M halves = 1M fl
#define WQKV_OFF  (SCR_OFF + 1048576)          // qkv_w f16: 3M halves = 1.5M fl
#define QKV16_OFF (SCR_OFF + 2621440)          // qkv f16: 6M halves = 3M fl
#define OP_OFF    (SCR_OFF)                    // partial O f16: KSPLIT*2M halves = 4M fl
#define ML_OFF    (SCR_OFF + 4194304)          // m,l f32: KSPLIT*16*2048*2 = 256K fl
#define Q_OFF     (SCR_OFF + 5767168)          // f16 2M halves = 1M fl
#define K_OFF     (Q_OFF + 1048576)
#define V_OFF     (K_OFF + 1048576)
#define OT_OFF    (V_OFF + 1048576)            // f16 2M halves
// total ~= 10.5M floats ~= 40 MB

// ---------------- async global->LDS (16B per lane, wave-uniform LDS base) ----------------
__device__ __forceinline__ void gl_lds16(const void* g, void* s) {
    __builtin_amdgcn_global_load_lds((const __attribute__((address_space(1))) void*)g,
                                     (__attribute__((address_space(3))) void*)s, 16, 0, 0);
}

// ---------------- cast x / qkv_w / proj_w to f16 + per-camera matrices (fused) ----------
__global__ __launch_bounds__(256) void cast_and_mats(const float* __restrict__ x,
                                                     const float* __restrict__ wqkv,
                                                     const float* __restrict__ wproj,
                                                     const float* __restrict__ ext,
                                                     const float* __restrict__ Ksm,
                                                     _Float16* __restrict__ xf,
                                                     _Float16* __restrict__ wqkvf,
                                                     _Float16* __restrict__ wprojf,
                                                     float* __restrict__ mats) {
    size_t i = ((size_t)blockIdx.x * 256 + threadIdx.x) * 8;
    const float* src; _Float16* dst; size_t off;
    if (i < (size_t)2*1024*1024)       { src = x;     dst = xf;     off = i; }
    else if (i < (size_t)5*1024*1024)  { src = wqkv;  dst = wqkvf;  off = i - (size_t)2*1024*1024; }
    else                               { src = wproj; dst = wprojf; off = i - (size_t)5*1024*1024; }
    float4 a = *(const float4*)(src + off);
    float4 b = *(const float4*)(src + off + 4);
    half8 h;
    h[0] = (_Float16)a.x; h[1] = (_Float16)a.y; h[2] = (_Float16)a.z; h[3] = (_Float16)a.w;
    h[4] = (_Float16)b.x; h[5] = (_Float16)b.y; h[6] = (_Float16)b.z; h[7] = (_Float16)b.w;
    *(half8*)(dst + off) = h;

    if (blockIdx.x == 0 && threadIdx.x < NCAMS) {
        const int c = threadIdx.x;
        const float sx = 2.0f / 448.0f, sy = 2.0f / 448.0f;
        const float* Kc = Ksm + c * 9;
        const float* E  = ext + c * 16;
        float Kn[16];
#pragma unroll
        for (int t = 0; t < 16; t++) Kn[t] = 0.0f;
        Kn[0]  = Kc[0] * sx;
        Kn[2]  = Kc[2] * sx - 1.0f;
        Kn[5]  = Kc[4] * sy;
        Kn[6]  = Kc[5] * sy - 1.0f;
        Kn[10] = 1.0f; Kn[15] = 1.0f;
        float P[16];
#pragma unroll
        for (int r = 0; r < 4; r++)
#pragma unroll
            for (int cc = 0; cc < 4; cc++) {
                float s = 0.0f;
#pragma unroll
                for (int k = 0; k < 4; k++) s += Kn[r*4+k] * E[k*4+cc];
                P[r*4+cc] = s;
            }
        float M[4][8];
        for (int r = 0; r < 4; r++)
            for (int cc = 0; cc < 4; cc++) { M[r][cc] = P[r*4+cc]; M[r][4+cc] = (r==cc) ? 1.0f : 0.0f; }
        for (int col = 0; col < 4; col++) {
            int piv = col;
            for (int r = col+1; r < 4; r++)
                if (fabsf(M[r][col]) > fabsf(M[piv][col])) piv = r;
            if (piv != col)
                for (int j = 0; j < 8; j++) { float tmp = M[col][j]; M[col][j] = M[piv][j]; M[piv][j] = tmp; }
            float d = 1.0f / M[col][col];
            for (int j = 0; j < 8; j++) M[col][j] *= d;
            for (int r = 0; r < 4; r++) {
                if (r == col) continue;
                float f = M[r][col];
                for (int j = 0; j < 8; j++) M[r][j] -= f * M[col][j];
            }
        }
        float Pi[16];
        for (int r = 0; r < 4; r++)
            for (int cc = 0; cc < 4; cc++) Pi[r*4+cc] = M[r][4+cc];
        float* o = mats + c * 48;
        for (int r = 0; r < 4; r++)
            for (int cc = 0; cc < 4; cc++) o[r*4+cc] = Pi[cc*4+r];  // Aq = Pinv^T
        for (int t = 0; t < 16; t++) o[16+t] = P[t];                // Ak = P
        for (int t = 0; t < 16; t++) o[32+t] = Pi[t];               // Ao = Pinv
    }
}

// ---------------- MFMA f16 GEMM: C[M][Nn] = A[M][K] . B[Nn][K]^T ----------------
// 64x128 tile, BK=32, double-buffered LDS, single barrier per K-step.
template <bool F16OUT>
__global__ __launch_bounds__(256) void gemm_mfma(const _Float16* __restrict__ A,
                                                 const _Float16* __restrict__ Bw,
                                                 const float* __restrict__ bias,
                                                 void* __restrict__ C,
                                                 int Nn, int Kd) {
    __shared__ _Float16 As[2][64 * 32];
    __shared__ _Float16 Bs[2][128 * 32];
    const int tid  = threadIdx.x;
    const int w    = tid >> 6, lane = tid & 63;
    const int ql   = lane & 15, quad = lane >> 4;
    const int lr   = lane >> 2, lc = lane & 3;
    const int row0 = blockIdx.y * 64, col0 = blockIdx.x * 128;

    floatx4 acc[4][2];
#pragma unroll
    for (int mt = 0; mt < 4; mt++)
#pragma unroll
        for (int nt = 0; nt < 2; nt++) acc[mt][nt] = (floatx4){0.f, 0.f, 0.f, 0.f};

    const _Float16* Ab  = A  + (size_t)(row0 + w * 16 + lr) * Kd + lc * 8;
    const _Float16* Bb0 = Bw + (size_t)(col0 + w * 32 + lr) * Kd + lc * 8;
    const _Float16* Bb1 = Bw + (size_t)(col0 + w * 32 + 16 + lr) * Kd + lc * 8;

    gl_lds16(Ab,  &As[0][(w * 16) * 32]);
    gl_lds16(Bb0, &Bs[0][(w * 32) * 32]);
    gl_lds16(Bb1, &Bs[0][(w * 32 + 16) * 32]);

    const int nIter = Kd >> 5;
    for (int i = 0; i < nIter; i++) {
        __syncthreads();
        if (i + 1 < nIter) {
            const int k0 = (i + 1) << 5;
            const int nb = (i + 1) & 1;
            gl_lds16(Ab + k0,  &As[nb][(w * 16) * 32]);
            gl_lds16(Bb0 + k0, &Bs[nb][(w * 32) * 32]);
            gl_lds16(Bb1 + k0, &Bs[nb][(w * 32 + 16) * 32]);
        }
        const int cur = i & 1;
        half8 af[4], bf[2];
#pragma unroll
        for (int mt = 0; mt < 4; mt++)
            af[mt] = *(const half8*)&As[cur][(mt * 16 + ql) * 32 + quad * 8];
#pragma unroll
        for (int nt = 0; nt < 2; nt++)
            bf[nt] = *(const half8*)&Bs[cur][(w * 32 + nt * 16 + ql) * 32 + quad * 8];
#pragma unroll
        for (int mt = 0; mt < 4; mt++)
#pragma unroll
            for (int nt = 0; nt < 2; nt++)
                acc[mt][nt] = __builtin_amdgcn_mfma_f32_16x16x32_f16(af[mt], bf[nt], acc[mt][nt], 0, 0, 0);
    }

#pragma unroll
    for (int nt = 0; nt < 2; nt++) {
        const int col = col0 + w * 32 + nt * 16 + ql;
        float bb = F16OUT ? 0.0f : bias[col];
#pragma unroll
        for (int mt = 0; mt < 4; mt++) {
            const int row = row0 + mt * 16 + quad * 4;
            if (F16OUT) {
                _Float16* Cp = (_Float16*)C;
#pragma unroll
                for (int r = 0; r < 4; r++)
                    Cp[(size_t)(row + r) * Nn + col] = (_Float16)acc[mt][nt][r];
            } else {
                float* Cp = (float*)C;
#pragma unroll
                for (int r = 0; r < 4; r++)
                    Cp[(size_t)(row + r) * Nn + col] = acc[mt][nt][r] + bb;
            }
        }
    }
}

// ---------------- fused PRoPE transform for Q, K, V (one launch) ----------------
// blocks [0, 2048):  Q/K,  T = ((n*2 + s)*16 + h)*8 + sub, coalesced in+out
// blocks [2048, 3072): V -> transposed [h][d][n], lane = token (coalesced stores)
// Q additionally scaled by 0.125 * log2(e)  (scores land in log2 domain)
__global__ __launch_bounds__(256) void transform_qkv(const _Float16* __restrict__ qkv,
                                                     const float* __restrict__ mats,
                                                     _Float16* __restrict__ Qf,
                                                     _Float16* __restrict__ Kf,
                                                     _Float16* __restrict__ Vtf) {
    const bool isV = blockIdx.x >= 2048;
    int n, h, sub, s;
    if (!isV) {
        const int T = blockIdx.x * 256 + threadIdx.x;
        sub = T & 7; h = (T >> 3) & 15; s = (T >> 7) & 1; n = T >> 8;
    } else {
        const int u = (blockIdx.x - 2048) * 256 + threadIdx.x;
        const int nl = u & 63;
        sub = (u >> 6) & 7; h = (u >> 9) & 15; n = (u >> 13) * 64 + nl; s = 2;
    }

    half8 v = *(const half8*)&qkv[(size_t)n * (3*DIM) + s * DIM + h * HD + sub * 8];
    float t[8];
#pragma unroll
    for (int i = 0; i < 8; i++) t[i] = (float)v[i];

    const int cam = n >> 10;
    const float* A = mats + cam * 48 + (s == 0 ? 0 : 16);
    float r[8];
    if (sub < 4) {
#pragma unroll
        for (int g = 0; g < 2; g++)
#pragma unroll
            for (int i = 0; i < 4; i++)
                r[g*4+i] = A[i*4+0]*t[g*4+0] + A[i*4+1]*t[g*4+1]
                         + A[i*4+2]*t[g*4+2] + A[i*4+3]*t[g*4+3];
    } else {
        const int p = n & (NPER - 1);
        const float px = (float)(p & 31), py = (float)(p >> 5);
        const int pt0 = (sub - 4) * 4;
#pragma unroll
        for (int pp = 0; pp < 4; pp++) {
            const int pt = pt0 + pp;
            const float fr = __expf(-0.5756462732485114f * (float)(pt & 7)); // 100^(-j/8)
            const float ang = (pt < NF ? px : py) * fr;
            float sn, cs; __sincosf(ang, &sn, &cs);
            const float a = t[pp*2], b = t[pp*2+1];
            r[pp*2]   = a * cs - b * sn;
            r[pp*2+1] = a * sn + b * cs;
        }
    }

    if (s == 0) {
        half8 o;
#pragma unroll
        for (int i = 0; i < 8; i++) o[i] = (_Float16)(r[i] * (0.125f * LOG2E));
        *(half8*)&Qf[((size_t)h * N_TOK + n) * HD + sub * 8] = o;
    } else if (s == 1) {
        half8 o;
#pragma unroll
        for (int i = 0; i < 8; i++) o[i] = (_Float16)r[i];
        *(half8*)&Kf[((size_t)h * N_TOK + n) * HD + sub * 8] = o;
    } else {
#pragma unroll
        for (int i = 0; i < 8; i++)
            Vtf[(size_t)(h * HD + sub * 8 + i) * N_TOK + n] = (_Float16)r[i];  // lane-coalesced
    }
}

// ---------------- MFMA flash attention: single-buffer LDS K/V, KSPLIT=4 ----------------
// Scores arrive in log2 domain (log2e folded into Q) -> exp2f softmax.
#define PLD 72   // 144B rows: 16B-aligned -> single ds_read_b128 P fragments
__global__ __launch_bounds__(256) void attn_mfma(const _Float16* __restrict__ Qh,
                                                 const _Float16* __restrict__ Kh,
                                                 const _Float16* __restrict__ Vt,
                                                 _Float16* __restrict__ OP,
                                                 float* __restrict__ ML) {
    __shared__ _Float16 sK[64 * 64];           // [key][dim], swizzled chunks
    __shared__ _Float16 sV[64 * 64];           // [dim][key], swizzled chunks
    __shared__ _Float16 P_lds[4][16][PLD];
    const int w    = threadIdx.x >> 6;
    const int lane = threadIdx.x & 63;
    const int b  = blockIdx.x;
    const int ks = b >> 9;
    const int hh = (b >> 5) & 15;
    const int qb = b & 31;
    const int ql = lane & 15, quad = lane >> 4;
    const int q0 = qb * 64 + w * 16;

    const int srow = lane >> 3;                // staging: row-in-8
    const int schk = (lane & 7) ^ srow;        // XOR-swizzled chunk
    const int c0 = ((quad ^ (ql & 7)) << 3);   // reader: chunk quad
    const int c1 = c0 ^ 32;                    // chunk quad+4

    const _Float16* Qp = Qh + ((size_t)hh * N_TOK + q0 + ql) * HD;
    const half8 qf0 = *(const half8*)(Qp + quad * 8);
    const half8 qf1 = *(const half8*)(Qp + 32 + quad * 8);

    const _Float16* Kb = Kh + (size_t)hh * N_TOK * HD;
    const _Float16* Vb = Vt + (size_t)hh * HD * N_TOK;

    floatx4 O[4];
#pragma unroll
    for (int mt = 0; mt < 4; mt++) O[mt] = (floatx4){0.f, 0.f, 0.f, 0.f};
    float m = -1e30f, l = 0.0f;   // l lane-local, reduced after loop; m in log2 units

    const int kstart = ks * (N_TOK / KSPLIT);
    const int nIter  = (N_TOK / KSPLIT) / 64;

    for (int i = 0; i < nIter; i++) {
        const int kb = kstart + i * 64;
#pragma unroll
        for (int j = 0; j < 2; j++) {
            const int r0 = w * 16 + j * 8;
            gl_lds16(Kb + (size_t)(kb + r0 + srow) * HD + schk * 8, &sK[r0 * 64]);
            gl_lds16(Vb + (size_t)(r0 + srow) * N_TOK + kb + schk * 8, &sV[r0 * 64]);
        }
        __syncthreads();
        // ---- S^T = K . Q^T from LDS fragments ----
        floatx4 s[4];
#pragma unroll
        for (int kt = 0; kt < 4; kt++) {
            const int rb = (kt * 16 + ql) * 64;
            half8 ka0 = *(const half8*)&sK[rb + c0];
            half8 ka1 = *(const half8*)&sK[rb + c1];
            floatx4 acc = (floatx4){0.f, 0.f, 0.f, 0.f};
            acc = __builtin_amdgcn_mfma_f32_16x16x32_f16(ka0, qf0, acc, 0, 0, 0);
            acc = __builtin_amdgcn_mfma_f32_16x16x32_f16(ka1, qf1, acc, 0, 0, 0);
            s[kt] = acc;
        }
        // ---- online softmax in log2 domain (2 cross-quad shuffles for m only) ----
        float bm = -1e30f;
#pragma unroll
        for (int kt = 0; kt < 4; kt++)
#pragma unroll
            for (int r = 0; r < 4; r++) bm = fmaxf(bm, s[kt][r]);
        bm = fmaxf(bm, __shfl_xor(bm, 16, 64));
        bm = fmaxf(bm, __shfl_xor(bm, 32, 64));
        const float mnew = fmaxf(m, bm);
        const float alpha = exp2f(m - mnew);
        float p[4][4];
        float ps = 0.0f;
#pragma unroll
        for (int kt = 0; kt < 4; kt++)
#pragma unroll
            for (int r = 0; r < 4; r++) { p[kt][r] = exp2f(s[kt][r] - mnew); ps += p[kt][r]; }
        l = l * alpha + ps;
        m = mnew;
#pragma unroll
        for (int mt = 0; mt < 4; mt++)
#pragma unroll
            for (int r = 0; r < 4; r++) O[mt][r] *= alpha;
        // ---- P -> per-wave LDS strip (packed b64 writes) -> b128 B-fragments ----
#pragma unroll
        for (int kt = 0; kt < 4; kt++) {
            union { half4h v; fp16x2 h[2]; } u;
            u.h[0] = __builtin_amdgcn_cvt_pkrtz(p[kt][0], p[kt][1]);
            u.h[1] = __builtin_amdgcn_cvt_pkrtz(p[kt][2], p[kt][3]);
            *(half4h*)&P_lds[w][ql][kt * 16 + quad * 4] = u.v;
        }
        half8 pf0 = *(const half8*)&P_lds[w][ql][quad * 8];
        half8 pf1 = *(const half8*)&P_lds[w][ql][32 + quad * 8];
        // ---- O^T += V^T . P from LDS fragments ----
#pragma unroll
        for (int mt = 0; mt < 4; mt++) {
            const int rb = (mt * 16 + ql) * 64;
            half8 va0 = *(const half8*)&sV[rb + c0];
            half8 va1 = *(const half8*)&sV[rb + c1];
            O[mt] = __builtin_amdgcn_mfma_f32_16x16x32_f16(va0, pf0, O[mt], 0, 0, 0);
            O[mt] = __builtin_amdgcn_mfma_f32_16x16x32_f16(va1, pf1, O[mt], 0, 0, 0);
        }
        __syncthreads();
    }
    // ---- final cross-quad l reduction ----
    l += __shfl_xor(l, 16, 64);
    l += __shfl_xor(l, 32, 64);
    const float rl = 1.0f / l;
    _Float16* Op = OP + (((size_t)(ks * HEADS + hh)) * N_TOK + q0 + ql) * HD;
#pragma unroll
    for (int mt = 0; mt < 4; mt++) {
        half4h o4;
#pragma unroll
        for (int r = 0; r < 4; r++) o4[r] = (_Float16)(O[mt][r] * rl);
        *(half4h*)&Op[mt * 16 + quad * 4] = o4;
    }
    if (quad == 0) {
        float2 mlv = {m, l};   // m in log2 units
        *(float2*)&ML[(((size_t)(ks * HEADS + hh)) * N_TOK + q0 + ql) * 2] = mlv;
    }
}

// ---------------- combine split-K partials + inverse PRoPE -> f16 token-major ----------------
__global__ __launch_bounds__(256) void transform_out(const _Float16* __restrict__ OP,
                                                     const float* __restrict__ ML,
                                                     const float* __restrict__ mats,
                                                     _Float16* __restrict__ Ot) {
    const int T = blockIdx.x * 256 + threadIdx.x;
    const int sub = T & 7;
    const int h   = (T >> 3) & 15;
    const int n   = T >> 7;

    half8 op[KSPLIT];
    float2 ml[KSPLIT];
#pragma unroll
    for (int i = 0; i < KSPLIT; i++) {
        op[i] = *(const half8*)&OP[(((size_t)(i * HEADS + h)) * N_TOK + n) * HD + sub * 8];
        ml[i] = *(const float2*)&ML[(((size_t)(i * HEADS + h)) * N_TOK + n) * 2];
    }
    float mstar = ml[0].x;
#pragma unroll
    for (int i = 1; i < KSPLIT; i++) mstar = fmaxf(mstar, ml[i].x);
    float W = 0.0f;
    float t[8] = {0.f, 0.f, 0.f, 0.f, 0.f, 0.f, 0.f, 0.f};
#pragma unroll
    for (int i = 0; i < KSPLIT; i++) {
        const float wgt = exp2f(ml[i].x - mstar) * ml[i].y;   // m stored in log2 units
        W += wgt;
#pragma unroll
        for (int d = 0; d < 8; d++) t[d] += wgt * (float)op[i][d];
    }
    const float rW = 1.0f / W;
#pragma unroll
    for (int d = 0; d < 8; d++) t[d] *= rW;

    const int cam = n >> 10;
    const float* A = mats + cam * 48 + 32;   // Ao = Pinv
    float r[8];
    if (sub < 4) {
#pragma unroll
        for (int g = 0; g < 2; g++)
#pragma unroll
            for (int i = 0; i < 4; i++)
                r[g*4+i] = A[i*4+0]*t[g*4+0] + A[i*4+1]*t[g*4+1]
                         + A[i*4+2]*t[g*4+2] + A[i*4+3]*t[g*4+3];
    } else {
        const int p = n & (NPER - 1);
        const float px = (float)(p & 31), py = (float)(p >> 5);
        const int pt0 = (sub - 4) * 4;
#pragma unroll
        for (int pp = 0; pp < 4; pp++) {
            const int pt = pt0 + pp;
            const float fr = __expf(-0.5756462732485114f * (float)(pt & 7));
            const float ang = (pt < NF ? px : py) * fr;
            float sn, cs; __sincosf(ang, &sn, &cs);
            const float a = t[pp*2], b = t[pp*2+1];
            r[pp*2]   = a * cs + b * sn;    // sign = -1
            r[pp*2+1] = -a * sn + b * cs;
        }
    }
    half8 o;
#pragma unroll
    for (int i = 0; i < 8; i++) o[i] = (_Float16)r[i];
    *(half8*)&Ot[(size_t)n * DIM + h * HD + sub * 8] = o;
}

// ---------------- launcher ----------------
extern "C" void kernel_launch(void* const* d_in, const int* in_sizes, int n_in,
                              void* d_out, int out_size, void* d_ws, size_t ws_size,
                              hipStream_t stream) {
    const float* x      = (const float*)d_in[0];
    const float* ext    = (const float*)d_in[1];
    const float* Ks     = (const float*)d_in[2];
    const float* qkv_w  = (const float*)d_in[3];
    const float* proj_w = (const float*)d_in[4];
    const float* proj_b = (const float*)d_in[5];
    float* out = (float*)d_out;

    float* ws   = (float*)d_ws;
    float* mats = ws + MATS_OFF;
    _Float16* Wprojf = (_Float16*)(ws + WPROJ_OFF);
    _Float16* Xf     = (_Float16*)(ws + XF_OFF);
    _Float16* Wqkvf  = (_Float16*)(ws + WQKV_OFF);
    _Float16* qkv16  = (_Float16*)(ws + QKV16_OFF);
    _Float16* OP     = (_Float16*)(ws + OP_OFF);
    float*    ML     = ws + ML_OFF;
    _Float16* Qf  = (_Float16*)(ws + Q_OFF);
    _Float16* Kf  = (_Float16*)(ws + K_OFF);
    _Float16* Vtf = (_Float16*)(ws + V_OFF);
    _Float16* Ot16 = (_Float16*)(ws + OT_OFF);

    cast_and_mats<<<3072, 256, 0, stream>>>(x, qkv_w, proj_w, ext, Ks,
                                            Xf, Wqkvf, Wprojf, mats);

    // qkv16 = x @ qkv_w^T : M=2048, Nn=3072, K=1024  (768 blocks = 3/CU)
    gemm_mfma<true><<<dim3(3*DIM/128, N_TOK/64), 256, 0, stream>>>(
        Xf, Wqkvf, nullptr, (void*)qkv16, 3*DIM, DIM);

    // fused Q/K/V transform: 2048 qk-blocks + 1024 v-blocks
    transform_qkv<<<3072, 256, 0, stream>>>(qkv16, mats, Qf, Kf, Vtf);

    attn_mfma<<<KSPLIT * HEADS * (N_TOK / 64), 256, 0, stream>>>(Qf, Kf, Vtf, OP, ML);

    transform_out<<<N_TOK * HEADS * 8 / 256, 256, 0, stream>>>(OP, ML, mats, Ot16);

    // out = Ot @ proj_w^T + proj_b : M=2048, Nn=1024, K=1024  (256 blocks = 1/CU)
    gemm_mfma<false><<<dim3(DIM/128, N_TOK/64), 256, 0, stream>>>(
        Ot16, Wprojf, proj_b, (void*)out, DIM, DIM);
}